// Round 1
// 520.037 us; speedup vs baseline: 1.0646x; 1.0646x over previous
//
#include <hip/hip_runtime.h>
#include <hip/hip_bf16.h>
#include <math.h>

#define T_IN 98304
#define SS 128
#define NBATCH 2
#define NN 256          // NBATCH*SS
#define C1 256
#define C2 512
#define C3 7168
#define NCBK 14
#define DIMV 512
#define VOC 1024
#define TOUT 97537
#define HOP 768

// ws layout (float offsets)
#define OFF_CBN    0L          // 14336
#define OFF_AB1    14336L      // 512
#define OFF_AB2    14848L      // 256
#define OFF_CCONST 15104L      // 16
#define OFF_H2C    15120L      // 131072   (n*512+ic), n=b*128+s
#define OFF_H2XH   146192L     // 196608 fl (ushort [256][1536] bf16-hi)
#define OFF_H2XL   342800L     // 196608 fl (bf16-lo)
#define OFF_H3H    539408L     // 917504 fl (ushort [256][7168] bf16-hi)
#define OFF_H3L    1456912L    // 917504 fl
#define OFF_SCORES 2374416L    // 3670016  ((k*256+n)*1024 + v)
// X1h/X1l (bf16 [256][1280] = 163840 fl each) OVERLAP scores region: X1 is dead
// before gemm_scores writes scores (same stream serializes).
#define OFF_X1H    2374416L    // ends 2538256
#define OFF_X1L    2538256L    // ends 2702096
// dw1t (bf16 [2560][7168] = 9175040 fl) OVERLAPS h3h/h3l/scores: all dead
// before k_dw1t runs (launched after k_argmin; same stream serializes).
#define OFF_DW1T   539408L     // ends 9714448
// Xh/Xl (bf16 [2304][2560] each = 2949120 fl each) OVERLAP dw1t: dw1t is dead
// after gemm_a1_mfma; k_x2 launches after it (same stream serializes).
#define OFF_XH     539408L     // ends 3488528
#define OFF_XL     3488528L    // ends 6437648
#define OFF_CODES  9714448L    // 3584 ints
#define OFF_QBF    9718032L    // 917504 fl (bf16 [256][7168])
#define OFF_A1RAW  10635536L   // 655360   ((n*5+j)*512 + c)  pre-bias/relu
#define OFF_A2ACT  11290896L   // 589824   ((n*9+u)*256 + o)  post-relu
// total 11880720 floats = 47.5 MB

typedef __attribute__((ext_vector_type(8))) short short8;
typedef __attribute__((ext_vector_type(4))) float f32x4;

static __device__ inline ushort f2bf(float x) {
  __hip_bfloat16 h = __float2bfloat16(x);
  return *reinterpret_cast<ushort*>(&h);
}

// exact 2-term split: x = hi + lo + O(2^-16 |x|); truncation split, residual exact
static __device__ inline void split8(const float4 x0, const float4 x1,
                                     short8& h, short8& l) {
  float xs[8] = {x0.x, x0.y, x0.z, x0.w, x1.x, x1.y, x1.z, x1.w};
  #pragma unroll
  for (int e = 0; e < 8; ++e) {
    uint b = __float_as_uint(xs[e]);
    h[e] = (short)(b >> 16);
    float r = xs[e] - __uint_as_float(b & 0xffff0000u);
    l[e] = (short)(__float_as_uint(r) >> 16);
  }
}

// ---------------- prep: codebook norms ----------------
__global__ void k_cbn(const float* __restrict__ cb, float* __restrict__ cbn) {
  int row = blockIdx.x * 4 + (threadIdx.x >> 6);
  int lane = threadIdx.x & 63;
  const float* p = cb + (long)row * DIMV;
  float s = 0.f;
  for (int d = lane; d < DIMV; d += 64) { float x = p[d]; s += x * x; }
  for (int off = 32; off; off >>= 1) s += __shfl_down(s, off);
  if (lane == 0) cbn[row] = s;
}

// ---------------- prep A: ab1 = relu(db1); ab2[o] = relu(db2[o]+sum_c W(o,c)*ab1[c])
__global__ __launch_bounds__(256) void k_prep_ab2(const float* __restrict__ db1,
    const float* __restrict__ dw2, const float* __restrict__ db2,
    float* __restrict__ ab1, float* __restrict__ ab2) {
  __shared__ float red[256];
  int o = blockIdx.x, t = threadIdx.x;
  if (o == 0) { ab1[t] = fmaxf(db1[t], 0.f); ab1[t + 256] = fmaxf(db1[t + 256], 0.f); }
  const float* wp = dw2 + (long)o * C2 * 5;
  float acc = 0.f;
  #pragma unroll
  for (int h = 0; h < 2; ++h) {
    int c = t + h * 256;
    const float* p = wp + c * 5;
    float wsum = p[0] + p[1] + p[2] + p[3] + p[4];
    acc = fmaf(wsum, fmaxf(db1[c], 0.f), acc);
  }
  red[t] = acc;
  __syncthreads();
  for (int off = 128; off; off >>= 1) {
    if (t < off) red[t] += red[t + off];
    __syncthreads();
  }
  if (t == 0) ab2[o] = fmaxf(red[0] + db2[o], 0.f);
}

// ---------------- prep B: cconst = tanh(db3 + sum_o (sum_j dw3[o][j]) * ab2[o]) ----
__global__ __launch_bounds__(256) void k_prep_c(const float* __restrict__ dw3,
    const float* __restrict__ db3, const float* __restrict__ ab2,
    float* __restrict__ cconst) {
  __shared__ float red[256];
  int t = threadIdx.x;
  float wsum3 = 0.f;
  #pragma unroll
  for (int j = 0; j < 7; ++j) wsum3 += dw3[t*7+j];
  red[t] = wsum3 * ab2[t];
  __syncthreads();
  for (int off = 128; off; off >>= 1) {
    if (t < off) red[t] += red[t + off];
    __syncthreads();
  }
  if (t == 0) cconst[0] = tanhf(red[0] + db3[0]);
}

// ---------------- encoder conv1 (k7,p3) at the 5 cols conv2 needs, as im2col ------
// X1[n][ic*5+jj] = h1[b][ic][768s+jj-2]  (0 if tcol<0: conv2 zero pad)
__global__ __launch_bounds__(256) void k_enc1(const float* __restrict__ audio,
    const float* __restrict__ ew1, const float* __restrict__ eb1,
    ushort* __restrict__ X1h, ushort* __restrict__ X1l) {
  int n = blockIdx.x, ic = threadIdx.x;
  int b = n >> 7, s = n & 127;
  const float* ap = audio + (long)b * T_IN;
  int base = HOP * s - 5;           // audio idx for window pos 0
  float a[11];
  #pragma unroll
  for (int w = 0; w < 11; ++w) {
    int ai = base + w;
    a[w] = (ai >= 0 && ai < T_IN) ? ap[ai] : 0.f;
  }
  float w1[7];
  #pragma unroll
  for (int j = 0; j < 7; ++j) w1[j] = ew1[ic*7+j];
  float b1 = eb1[ic];
  long off = (long)n * 1280 + ic * 5;
  #pragma unroll
  for (int jj = 0; jj < 5; ++jj) {
    int tcol = HOP * s + jj - 2;
    float v = 0.f;
    if (tcol >= 0) {
      float acc = b1;
      #pragma unroll
      for (int j = 0; j < 7; ++j) acc = fmaf(w1[j], a[jj + j], acc);
      v = fmaxf(acc, 0.f);
    }
    uint bi = __float_as_uint(v);
    X1h[off + jj] = (ushort)(bi >> 16);
    float r = v - __uint_as_float(bi & 0xffff0000u);
    X1l[off + jj] = (ushort)(__float_as_uint(r) >> 16);
  }
}

// ---------------- encoder conv2 as GEMM: h2c[n][oc] = relu(eb2 + ew2 . X1^T) ------
// A = ew2 fp32 [512][1280] (OTF split; layout [oc][ic*5+jj] matches X1's k),
// B = X1 splits [256][1280]; 3xBF16 MFMA, no-LDS 1-wave blocks, grid (16, 4)
__global__ __launch_bounds__(64) void gemm_enc2(const float* __restrict__ ew2,
    const ushort* __restrict__ X1h, const ushort* __restrict__ X1l,
    const float* __restrict__ eb2, float* __restrict__ h2c) {
  const int t = threadIdx.x;
  const int l15 = t & 15, quad = t >> 4;
  const int m0 = blockIdx.x * 32, n0 = blockIdx.y * 64;
  f32x4 acc[2][4] = {};
  const float*  aB = ew2 + (long)(m0 + l15) * 1280 + quad * 8;
  const ushort* bhB = X1h + (long)(n0 + l15) * 1280 + quad * 8;
  const ushort* blB = X1l + (long)(n0 + l15) * 1280 + quad * 8;
  for (int k0 = 0; k0 < 1280; k0 += 32) {
    short8 ah[2], al[2], bh[4], bl[4];
    #pragma unroll
    for (int f = 0; f < 2; ++f) {
      const float* ap = aB + (long)f * 16 * 1280 + k0;
      float4 x0 = *(const float4*)ap;
      float4 x1 = *(const float4*)(ap + 4);
      split8(x0, x1, ah[f], al[f]);
    }
    #pragma unroll
    for (int f = 0; f < 4; ++f) {
      bh[f] = *(const short8*)(bhB + (long)f * 16 * 1280 + k0);
      bl[f] = *(const short8*)(blB + (long)f * 16 * 1280 + k0);
    }
    #pragma unroll
    for (int i = 0; i < 2; ++i)
      #pragma unroll
      for (int j = 0; j < 4; ++j) {
        acc[i][j] = __builtin_amdgcn_mfma_f32_16x16x32_bf16(ah[i], bh[j], acc[i][j], 0, 0, 0);
        acc[i][j] = __builtin_amdgcn_mfma_f32_16x16x32_bf16(ah[i], bl[j], acc[i][j], 0, 0, 0);
        acc[i][j] = __builtin_amdgcn_mfma_f32_16x16x32_bf16(al[i], bh[j], acc[i][j], 0, 0, 0);
      }
  }
  #pragma unroll
  for (int i = 0; i < 2; ++i) {
    const int obase = m0 + i * 16 + quad * 4;
    float4 bias = *(const float4*)(eb2 + obase);
    #pragma unroll
    for (int j = 0; j < 4; ++j) {
      const int n = n0 + j * 16 + l15;
      float4 out;
      out.x = fmaxf(acc[i][j][0] + bias.x, 0.f);
      out.y = fmaxf(acc[i][j][1] + bias.y, 0.f);
      out.z = fmaxf(acc[i][j][2] + bias.z, 0.f);
      out.w = fmaxf(acc[i][j][3] + bias.w, 0.f);
      *(float4*)(h2c + (long)n * C2 + obase) = out;
    }
  }
}

// ---------------- im2col for conv3 (k3,p1), written as bf16 hi/lo split ----------
__global__ void k_h2x(const float* __restrict__ h2c, ushort* __restrict__ h2xh,
                      ushort* __restrict__ h2xl) {
  int idx = blockIdx.x * 256 + threadIdx.x;
  const int total = NN * 1536;
  for (; idx < total; idx += gridDim.x * 256) {
    int n = idx / 1536, r = idx - n * 1536;
    int ic = r / 3, j = r - ic * 3;
    int s2 = (n & 127) + j - 1;
    int b = n >> 7;
    float v = (s2 >= 0 && s2 < SS) ? h2c[(long)(b*SS + s2)*C2 + ic] : 0.f;
    uint bi = __float_as_uint(v);
    h2xh[idx] = (ushort)(bi >> 16);
    float rr = v - __uint_as_float(bi & 0xffff0000u);
    h2xl[idx] = (ushort)(__float_as_uint(rr) >> 16);
  }
}

// ---------------- S1: h3 = ew3 . h2x^T + eb3, 3xBF16 MFMA, no-LDS 1-wave blocks ----
__global__ __launch_bounds__(64) void gemm_h3(const float* __restrict__ A,
    const ushort* __restrict__ Bh, const ushort* __restrict__ Bl,
    const float* __restrict__ eb3, ushort* __restrict__ h3h, ushort* __restrict__ h3l) {
  const int t = threadIdx.x;
  const int l15 = t & 15, quad = t >> 4;
  const int m0 = blockIdx.x * 64, n0 = blockIdx.y * 64;
  f32x4 acc[4][4] = {};
  const float*  aB = A  + (long)(m0 + l15) * 1536 + quad * 8;
  const ushort* bhB = Bh + (long)(n0 + l15) * 1536 + quad * 8;
  const ushort* blB = Bl + (long)(n0 + l15) * 1536 + quad * 8;
  for (int k0 = 0; k0 < 1536; k0 += 32) {
    short8 ah[4], al[4], bh[4], bl[4];
    #pragma unroll
    for (int f = 0; f < 4; ++f) {
      const float* ap = aB + (long)f * 16 * 1536 + k0;
      float4 x0 = *(const float4*)ap;
      float4 x1 = *(const float4*)(ap + 4);
      split8(x0, x1, ah[f], al[f]);
      bh[f] = *(const short8*)(bhB + (long)f * 16 * 1536 + k0);
      bl[f] = *(const short8*)(blB + (long)f * 16 * 1536 + k0);
    }
    #pragma unroll
    for (int i = 0; i < 4; ++i)
      #pragma unroll
      for (int j = 0; j < 4; ++j) {
        acc[i][j] = __builtin_amdgcn_mfma_f32_16x16x32_bf16(ah[i], bh[j], acc[i][j], 0, 0, 0);
        acc[i][j] = __builtin_amdgcn_mfma_f32_16x16x32_bf16(ah[i], bl[j], acc[i][j], 0, 0, 0);
        acc[i][j] = __builtin_amdgcn_mfma_f32_16x16x32_bf16(al[i], bh[j], acc[i][j], 0, 0, 0);
      }
  }
  #pragma unroll
  for (int i = 0; i < 4; ++i) {
    const int mbase = m0 + i * 16 + quad * 4;
    float4 bias = *(const float4*)(eb3 + mbase);
    #pragma unroll
    for (int j = 0; j < 4; ++j) {
      const int n = n0 + j * 16 + l15;
      float v0 = acc[i][j][0] + bias.x;
      float v1 = acc[i][j][1] + bias.y;
      float v2 = acc[i][j][2] + bias.z;
      float v3 = acc[i][j][3] + bias.w;
      uint b0 = __float_as_uint(v0), b1 = __float_as_uint(v1);
      uint b2 = __float_as_uint(v2), b3 = __float_as_uint(v3);
      uint2 hp;
      hp.x = (b0 >> 16) | (b1 & 0xffff0000u);
      hp.y = (b2 >> 16) | (b3 & 0xffff0000u);
      float r0 = v0 - __uint_as_float(b0 & 0xffff0000u);
      float r1 = v1 - __uint_as_float(b1 & 0xffff0000u);
      float r2 = v2 - __uint_as_float(b2 & 0xffff0000u);
      float r3 = v3 - __uint_as_float(b3 & 0xffff0000u);
      uint2 lp;
      lp.x = (__float_as_uint(r0) >> 16) | (__float_as_uint(r1) & 0xffff0000u);
      lp.y = (__float_as_uint(r2) >> 16) | (__float_as_uint(r3) & 0xffff0000u);
      long off = (long)n * C3 + mbase;
      *(uint2*)(h3h + off) = hp;
      *(uint2*)(h3l + off) = lp;
    }
  }
}

// ---------------- S2: scores = cbn - 2*cb.h3^T, 3xBF16 MFMA, no-LDS 1-wave blocks --
__global__ __launch_bounds__(64) void gemm_scores(const float* __restrict__ cb,
    const ushort* __restrict__ h3h, const ushort* __restrict__ h3l,
    const float* __restrict__ cbn, float* __restrict__ scores) {
  const int t = threadIdx.x;
  const int l15 = t & 15, quad = t >> 4;
  const int m0 = blockIdx.x * 64, n0 = blockIdx.y * 64, z = blockIdx.z;
  f32x4 acc[4][4] = {};
  const float*  aB = cb + (long)z * VOC * DIMV + (long)(m0 + l15) * 512 + quad * 8;
  const ushort* bhB = h3h + (long)(n0 + l15) * C3 + z * 512 + quad * 8;
  const ushort* blB = h3l + (long)(n0 + l15) * C3 + z * 512 + quad * 8;
  for (int k0 = 0; k0 < 512; k0 += 32) {
    short8 ah[4], al[4], bh[4], bl[4];
    #pragma unroll
    for (int f = 0; f < 4; ++f) {
      const float* ap = aB + (long)f * 16 * 512 + k0;
      float4 x0 = *(const float4*)ap;
      float4 x1 = *(const float4*)(ap + 4);
      split8(x0, x1, ah[f], al[f]);
      bh[f] = *(const short8*)(bhB + (long)f * 16 * C3 + k0);
      bl[f] = *(const short8*)(blB + (long)f * 16 * C3 + k0);
    }
    #pragma unroll
    for (int i = 0; i < 4; ++i)
      #pragma unroll
      for (int j = 0; j < 4; ++j) {
        acc[i][j] = __builtin_amdgcn_mfma_f32_16x16x32_bf16(ah[i], bh[j], acc[i][j], 0, 0, 0);
        acc[i][j] = __builtin_amdgcn_mfma_f32_16x16x32_bf16(ah[i], bl[j], acc[i][j], 0, 0, 0);
        acc[i][j] = __builtin_amdgcn_mfma_f32_16x16x32_bf16(al[i], bh[j], acc[i][j], 0, 0, 0);
      }
  }
  #pragma unroll
  for (int i = 0; i < 4; ++i) {
    const int vbase = m0 + i * 16 + quad * 4;
    float4 cn = *(const float4*)(cbn + z * VOC + vbase);
    #pragma unroll
    for (int j = 0; j < 4; ++j) {
      const int n = n0 + j * 16 + l15;
      float4 out;
      out.x = cn.x - 2.f * acc[i][j][0];
      out.y = cn.y - 2.f * acc[i][j][1];
      out.z = cn.z - 2.f * acc[i][j][2];
      out.w = cn.w - 2.f * acc[i][j][3];
      *(float4*)(scores + ((long)z * NN + n) * VOC + vbase) = out;
    }
  }
}

// ---------------- argmin over 1024 codes, numpy tie-break (lowest v) ----------------
__global__ void k_argmin(const float* __restrict__ scores, int* __restrict__ codes) {
  int row = blockIdx.x;          // k*256+n
  int lane = threadIdx.x;        // 64
  const float* p = scores + (long)row * VOC;
  float best = 3.4e38f; int bi = 0;
  for (int i = 0; i < 16; ++i) {
    int v = i * 64 + lane;
    float x = p[v];
    if (x < best) { best = x; bi = v; }
  }
  for (int off = 32; off; off >>= 1) {
    float ob = __shfl_down(best, off);
    int oi = __shfl_down(bi, off);
    if (ob < best || (ob == best && oi < bi)) { best = ob; bi = oi; }
  }
  if (lane == 0) codes[row] = bi;
}

// ---------------- transpose+convert dw1 [7168][2560] fp32 -> dw1t [2560][7168] bf16 ----
__global__ __launch_bounds__(256) void k_dw1t(const float* __restrict__ dw1,
                                              ushort* __restrict__ dw1t) {
  __shared__ __align__(16) ushort T[64 * 72];   // [m][k] tile, pitch 72
  int t = threadIdx.x;
  int k0 = blockIdx.x * 64, m0 = blockIdx.y * 64;
  int kk = t >> 2, mj = (t & 3) * 16;
  const float* src = dw1 + (long)(k0 + kk) * 2560 + m0 + mj;
  float x[16];
  *(float4*)&x[0]  = *(const float4*)(src);
  *(float4*)&x[4]  = *(const float4*)(src + 4);
  *(float4*)&x[8]  = *(const float4*)(src + 8);
  *(float4*)&x[12] = *(const float4*)(src + 12);
  #pragma unroll
  for (int l = 0; l < 16; ++l)
    T[(mj + l) * 72 + kk] = f2bf(x[l]);
  __syncthreads();
  int mo = t >> 2, kc = (t & 3) * 16;
  uint4 u0 = *(const uint4*)&T[mo * 72 + kc];
  uint4 u1 = *(const uint4*)&T[mo * 72 + kc + 8];
  ushort* dst = dw1t + (long)(m0 + mo) * C3 + k0 + kc;
  *(uint4*)dst = u0;
  *(uint4*)(dst + 8) = u1;
}

// ---------------- gather q as bf16: qbf[n][k*512+d] = bf16(cb[k, code, d]) ----------
__global__ void k_gather_qbf(const float* __restrict__ cb, const int* __restrict__ codes,
                             ushort* __restrict__ qbf) {
  int idx = blockIdx.x * 256 + threadIdx.x;      // pair index
  const int total = NN * C3 / 2;                 // 917504
  if (idx >= total) return;
  int n = idx / 3584, rr = idx - n * 3584;       // rr = k*256 + dp
  int k = rr >> 8, dp = rr & 255;
  int code = codes[k * NN + n];
  const float* s = cb + ((long)(k * VOC + code)) * DIMV + dp * 2;
  uint lo = f2bf(s[0]), hi = f2bf(s[1]);
  ((uint*)qbf)[idx] = lo | (hi << 16);
}

// ---------------- decoder convT GEMM via MFMA bf16 ----------------
// Rewritten: no-LDS direct bf16 fragment loads (gemm_h3 pattern), zero barriers
// in the K-loop. 4 waves per block each own a disjoint K-quarter (1792) of the
// same 64x64 output tile; one-shot LDS tree-reduce at the end.
// Old version: 224 iters x 2 __syncthreads with 1 wave/SIMD -> latency-serialized
// (94 us, MfmaUtil 3.7%, 4.6M LDS bank conflicts).
__global__ __launch_bounds__(256) void gemm_a1_mfma(const ushort* __restrict__ dw1t,
    const ushort* __restrict__ qbf, float* __restrict__ a1raw) {
  // red[wave][chunk=i*4+j][lane] as float4 -> 4*16*64*4 floats = 64 KB
  __shared__ __align__(16) float red[4 * 4096];
  const int tid = threadIdx.x;
  const int w = tid >> 6, lane = tid & 63;
  const int l15 = lane & 15, quad = lane >> 4;
  const int m0 = blockIdx.x * 64, n0 = blockIdx.y * 64;
  const int kbase = w * 1792;                 // disjoint K-quarter per wave
  f32x4 acc[4][4] = {};
  const ushort* aB = dw1t + (long)(m0 + l15) * C3 + kbase + quad * 8;
  const ushort* bB = qbf  + (long)(n0 + l15) * C3 + kbase + quad * 8;
  #pragma unroll 2
  for (int k0 = 0; k0 < 1792; k0 += 32) {
    short8 ah[4], bh[4];
    #pragma unroll
    for (int f = 0; f < 4; ++f) {
      ah[f] = *(const short8*)(aB + (long)f * 16 * C3 + k0);
      bh[f] = *(const short8*)(bB + (long)f * 16 * C3 + k0);
    }
    #pragma unroll
    for (int i = 0; i < 4; ++i)
      #pragma unroll
      for (int j = 0; j < 4; ++j)
        acc[i][j] = __builtin_amdgcn_mfma_f32_16x16x32_bf16(ah[i], bh[j], acc[i][j], 0, 0, 0);
  }
  // stash partials: region w, chunk (i*4+j), lane-contiguous float4 (conflict-free)
  #pragma unroll
  for (int i = 0; i < 4; ++i)
    #pragma unroll
    for (int j = 0; j < 4; ++j)
      *(float4*)&red[w * 4096 + (i * 4 + j) * 256 + lane * 4] = *(float4*)&acc[i][j];
  __syncthreads();
  // wave w reduces the 4 K-partials for row-block i=w and scatters to a1raw
  #pragma unroll
  for (int j = 0; j < 4; ++j) {
    float4 s = *(const float4*)&red[(w * 4 + j) * 256 + lane * 4];
    #pragma unroll
    for (int r = 1; r < 4; ++r) {
      float4 tt = *(const float4*)&red[r * 4096 + (w * 4 + j) * 256 + lane * 4];
      s.x += tt.x; s.y += tt.y; s.z += tt.z; s.w += tt.w;
    }
    const int n = n0 + j * 16 + l15;
    const int mb = m0 + w * 16 + quad * 4;
    float v[4] = {s.x, s.y, s.z, s.w};
    #pragma unroll
    for (int reg = 0; reg < 4; ++reg) {
      int m = mb + reg;
      int c = m / 5, jj = m - c * 5;
      a1raw[((long)(n * 5 + jj)) * C2 + c] = v[reg];
    }
  }
}

// ---------------- k_x2: build conv2 im2col X (bf16 hi/lo) from a1raw/ab1 ----------
__global__ void k_x2(const float* __restrict__ a1raw, const float* __restrict__ ab1g,
                     const float* __restrict__ db1, ushort* __restrict__ Xh,
                     ushort* __restrict__ Xl) {
  int idx = blockIdx.x * 256 + threadIdx.x;
  const int total = 2304 * 2560;
  for (; idx < total; idx += gridDim.x * 256) {
    int nu = idx / 2560, ck = idx - nu * 2560;
    int n = nu / 9, u = nu - n * 9;
    int c = ck / 5, jj = ck - c * 5;
    int w = u + jj;
    int s = n & 127;
    int tc = HOP * s - 6 + w;
    float v;
    if (tc < 0 || tc > TOUT - 1) v = 0.f;
    else if (w >= 4 && w <= 8)
      v = fmaxf(db1[c] + a1raw[((long)(n * 5 + (w - 4))) * C2 + c], 0.f);
    else v = ab1g[c];
    uint bi = __float_as_uint(v);
    Xh[idx] = (ushort)(bi >> 16);
    float rr = v - __uint_as_float(bi & 0xffff0000u);
    Xl[idx] = (ushort)(__float_as_uint(rr) >> 16);
  }
}

// ---------------- decoder conv2 as GEMM: a2act = relu(db2 + dw2 . X^T) ----------
__global__ __launch_bounds__(64) void gemm_dec2(const float* __restrict__ dw2,
    const ushort* __restrict__ Xh, const ushort* __restrict__ Xl,
    const float* __restrict__ db2, float* __restrict__ a2act) {
  const int t = threadIdx.x;
  const int l15 = t & 15, quad = t >> 4;
  const int m0 = blockIdx.x * 64, n0 = blockIdx.y * 64;
  f32x4 acc[4][4] = {};
  const float*  aB = dw2 + (long)(m0 + l15) * 2560 + quad * 8;
  const ushort* bhB = Xh + (long)(n0 + l15) * 2560 + quad * 8;
  const ushort* blB = Xl + (long)(n0 + l15) * 2560 + quad * 8;
  for (int k0 = 0; k0 < 2560; k0 += 32) {
    short8 ah[4], al[4], bh[4], bl[4];
    #pragma unroll
    for (int f = 0; f < 4; ++f) {
      const float* ap = aB + (long)f * 16 * 2560 + k0;
      float4 x0 = *(const float4*)ap;
      float4 x1 = *(const float4*)(ap + 4);
      split8(x0, x1, ah[f], al[f]);
      bh[f] = *(const short8*)(bhB + (long)f * 16 * 2560 + k0);
      bl[f] = *(const short8*)(blB + (long)f * 16 * 2560 + k0);
    }
    #pragma unroll
    for (int i = 0; i < 4; ++i)
      #pragma unroll
      for (int j = 0; j < 4; ++j) {
        acc[i][j] = __builtin_amdgcn_mfma_f32_16x16x32_bf16(ah[i], bh[j], acc[i][j], 0, 0, 0);
        acc[i][j] = __builtin_amdgcn_mfma_f32_16x16x32_bf16(ah[i], bl[j], acc[i][j], 0, 0, 0);
        acc[i][j] = __builtin_amdgcn_mfma_f32_16x16x32_bf16(al[i], bh[j], acc[i][j], 0, 0, 0);
      }
  }
  #pragma unroll
  for (int i = 0; i < 4; ++i) {
    const int obase = m0 + i * 16 + quad * 4;
    float4 bias = *(const float4*)(db2 + obase);
    #pragma unroll
    for (int j = 0; j < 4; ++j) {
      const int nu = n0 + j * 16 + l15;
      float4 out;
      out.x = fmaxf(acc[i][j][0] + bias.x, 0.f);
      out.y = fmaxf(acc[i][j][1] + bias.y, 0.f);
      out.z = fmaxf(acc[i][j][2] + bias.z, 0.f);
      out.w = fmaxf(acc[i][j][3] + bias.w, 0.f);
      *(float4*)(a2act + (long)nu * C1 + obase) = out;
    }
  }
}

// ---------------- fill output with the constant tanh value ----------------
__global__ void k_fill(float* __restrict__ outp, const float* __restrict__ cconst) {
  float v = cconst[0];
  int idx = blockIdx.x * 256 + threadIdx.x;
  const int total = NBATCH * TOUT;
  for (; idx < total; idx += gridDim.x * 256) outp[idx] = v;
}

// ---------------- decoder conv3+tanh on 15 active cols per (b,s) ----------------
__global__ __launch_bounds__(256) void k_dec3(const float* __restrict__ a2act,
    const float* __restrict__ ab2g, const float* __restrict__ dw3,
    const float* __restrict__ db3, float* __restrict__ outp) {
  __shared__ float sa2[9 * C1];
  __shared__ float sb[C1];
  int n = blockIdx.x;
  int s = n & 127, b = n >> 7;
  int t = threadIdx.x;
  for (int i = t; i < 9 * C1; i += 256) sa2[i] = a2act[(long)n * 9 * C1 + i];
  sb[t] = ab2g[t];
  __syncthreads();
  int wv = t >> 6, lane = t & 63;
  float b3 = db3[0];
  for (int w15 = wv; w15 < 15; w15 += 4) {
    int tc = HOP * s - 7 + w15;
    if (tc < 0 || tc > TOUT - 1) continue;
    float part = 0.f;
    for (int cc = lane; cc < C1; cc += 64) {
      #pragma unroll
      for (int j = 0; j < 7; ++j) {
        int wcol = tc + j - 3;
        float x;
        if (wcol < 0 || wcol > TOUT - 1) x = 0.f;
        else {
          int du = wcol - (HOP * s - 4);
          x = (du >= 0 && du <= 8) ? sa2[du * C1 + cc] : sb[cc];
        }
        part = fmaf(dw3[cc*7+j], x, part);
      }
    }
    for (int off = 32; off; off >>= 1) part += __shfl_down(part, off);
    if (lane == 0) outp[(long)b * TOUT + tc] = tanhf(part + b3);
  }
}

extern "C" void kernel_launch(void* const* d_in, const int* in_sizes, int n_in,
                              void* d_out, int out_size, void* d_ws, size_t ws_size,
                              hipStream_t stream) {
  const float* audio = (const float*)d_in[0];
  const float* cb    = (const float*)d_in[1];
  const float* ew1   = (const float*)d_in[2];
  const float* eb1   = (const float*)d_in[3];
  const float* ew2   = (const float*)d_in[4];
  const float* eb2   = (const float*)d_in[5];
  const float* ew3   = (const float*)d_in[6];
  const float* eb3   = (const float*)d_in[7];
  const float* dw1   = (const float*)d_in[8];
  const float* db1   = (const float*)d_in[9];
  const float* dw2   = (const float*)d_in[10];
  const float* db2   = (const float*)d_in[11];
  const float* dw3   = (const float*)d_in[12];
  const float* db3   = (const float*)d_in[13];
  float* outp = (float*)d_out;
  float* ws = (float*)d_ws;

  float*  cbn    = ws + OFF_CBN;
  float*  ab1    = ws + OFF_AB1;
  float*  ab2    = ws + OFF_AB2;
  float*  cconst = ws + OFF_CCONST;
  float*  h2c    = ws + OFF_H2C;
  ushort* h2xh   = (ushort*)(ws + OFF_H2XH);
  ushort* h2xl   = (ushort*)(ws + OFF_H2XL);
  ushort* h3h    = (ushort*)(ws + OFF_H3H);
  ushort* h3l    = (ushort*)(ws + OFF_H3L);
  float*  scores = ws + OFF_SCORES;
  ushort* X1h    = (ushort*)(ws + OFF_X1H);
  ushort* X1l    = (ushort*)(ws + OFF_X1L);
  ushort* dw1t   = (ushort*)(ws + OFF_DW1T);
  ushort* Xh     = (ushort*)(ws + OFF_XH);
  ushort* Xl     = (ushort*)(ws + OFF_XL);
  int*    codes  = (int*)(ws + OFF_CODES);
  ushort* qbf    = (ushort*)(ws + OFF_QBF);
  float*  a1raw  = ws + OFF_A1RAW;
  float*  a2act  = ws + OFF_A2ACT;

  k_cbn<<<3584, 256, 0, stream>>>(cb, cbn);
  k_prep_ab2<<<C1, 256, 0, stream>>>(db1, dw2, db2, ab1, ab2);
  k_prep_c<<<1, 256, 0, stream>>>(dw3, db3, ab2, cconst);
  k_enc1<<<NN, 256, 0, stream>>>(audio, ew1, eb1, X1h, X1l);
  gemm_enc2<<<dim3(16, 4), 64, 0, stream>>>(ew2, X1h, X1l, eb2, h2c);
  k_h2x<<<384, 256, 0, stream>>>(h2c, h2xh, h2xl);
  gemm_h3<<<dim3(112, 4), 64, 0, stream>>>(ew3, h2xh, h2xl, eb3, h3h, h3l);
  // gemm_scores writes over X1h/X1l (dead after gemm_enc2) — stream-ordered
  gemm_scores<<<dim3(16, 4, 14), 64, 0, stream>>>(cb, h3h, h3l, cbn, scores);
  k_argmin<<<NCBK * NN, 64, 0, stream>>>(scores, codes);
  // dw1t overlaps h3h/h3l/scores memory: must launch AFTER k_argmin (stream-ordered)
  k_dw1t<<<dim3(112, 40), 256, 0, stream>>>(dw1, dw1t);
  k_gather_qbf<<<3584, 256, 0, stream>>>(cb, codes, qbf);
  gemm_a1_mfma<<<dim3(40, 4), 256, 0, stream>>>(dw1t, qbf, a1raw);
  // Xh/Xl overlap dw1t memory: must launch AFTER gemm_a1_mfma (stream-ordered)
  k_x2<<<4096, 256, 0, stream>>>(a1raw, ab1, db1, Xh, Xl);
  gemm_dec2<<<dim3(4, 36), 64, 0, stream>>>(dw2, Xh, Xl, db2, a2act);
  k_fill<<<256, 256, 0, stream>>>(outp, cconst);
  k_dec3<<<NN, 256, 0, stream>>>(a2act, ab2, dw3, db3, outp);
}

// Round 2
// 480.418 us; speedup vs baseline: 1.1524x; 1.0825x over previous
//
#include <hip/hip_runtime.h>
#include <hip/hip_bf16.h>
#include <math.h>

#define T_IN 98304
#define SS 128
#define NBATCH 2
#define NN 256          // NBATCH*SS
#define C1 256
#define C2 512
#define C3 7168
#define NCBK 14
#define DIMV 512
#define VOC 1024
#define TOUT 97537
#define HOP 768

// ws layout (float offsets)
#define OFF_CBN    0L          // 14336
#define OFF_AB1    14336L      // 512
#define OFF_AB2    14848L      // 256
#define OFF_CCONST 15104L      // 16
#define OFF_H2C    15120L      // 131072   (n*512+ic), n=b*128+s
#define OFF_H2XH   146192L     // 196608 fl (ushort [256][1536] bf16-hi)
#define OFF_H2XL   342800L     // 196608 fl (bf16-lo)
#define OFF_H3H    539408L     // 917504 fl (ushort [256][7168] bf16-hi)
#define OFF_H3L    1456912L    // 917504 fl
#define OFF_SCORES 2374416L    // 3670016  ((k*256+n)*1024 + v)
// X1h/X1l (bf16 [256][1280] = 163840 fl each) OVERLAP scores region: X1 is dead
// before gemm_scores writes scores (same stream serializes).
#define OFF_X1H    2374416L    // ends 2538256
#define OFF_X1L    2538256L    // ends 2702096
// dw1t (bf16 [2560][7168] = 9175040 fl) OVERLAPS h3h/h3l/scores: all dead
// before k_dw1t runs (launched after k_argmin; same stream serializes).
#define OFF_DW1T   539408L     // ends 9714448
// Xh/Xl (bf16 [2304][2560] each = 2949120 fl each) OVERLAP dw1t: dw1t is dead
// after gemm_a1_mfma; k_x2 launches after it (same stream serializes).
#define OFF_XH     539408L     // ends 3488528
#define OFF_XL     3488528L    // ends 6437648
#define OFF_CODES  9714448L    // 3584 ints
#define OFF_QBF    9718032L    // 917504 fl (bf16 [256][7168])
#define OFF_A1RAW  10635536L   // 655360   ((n*5+j)*512 + c)  pre-bias/relu
#define OFF_A2ACT  11290896L   // 589824   ((n*9+u)*256 + o)  post-relu
// total 11880720 floats = 47.5 MB

typedef __attribute__((ext_vector_type(8))) short short8;
typedef __attribute__((ext_vector_type(4))) float f32x4;

static __device__ inline ushort f2bf(float x) {
  __hip_bfloat16 h = __float2bfloat16(x);
  return *reinterpret_cast<ushort*>(&h);
}

// exact 2-term split: x = hi + lo + O(2^-16 |x|); truncation split, residual exact
static __device__ inline void split8(const float4 x0, const float4 x1,
                                     short8& h, short8& l) {
  float xs[8] = {x0.x, x0.y, x0.z, x0.w, x1.x, x1.y, x1.z, x1.w};
  #pragma unroll
  for (int e = 0; e < 8; ++e) {
    uint b = __float_as_uint(xs[e]);
    h[e] = (short)(b >> 16);
    float r = xs[e] - __uint_as_float(b & 0xffff0000u);
    l[e] = (short)(__float_as_uint(r) >> 16);
  }
}

// ---------------- prep: codebook norms ----------------
__global__ void k_cbn(const float* __restrict__ cb, float* __restrict__ cbn) {
  int row = blockIdx.x * 4 + (threadIdx.x >> 6);
  int lane = threadIdx.x & 63;
  const float* p = cb + (long)row * DIMV;
  float s = 0.f;
  for (int d = lane; d < DIMV; d += 64) { float x = p[d]; s += x * x; }
  for (int off = 32; off; off >>= 1) s += __shfl_down(s, off);
  if (lane == 0) cbn[row] = s;
}

// ---------------- prep A: ab1 = relu(db1); ab2[o] = relu(db2[o]+sum_c W(o,c)*ab1[c])
__global__ __launch_bounds__(256) void k_prep_ab2(const float* __restrict__ db1,
    const float* __restrict__ dw2, const float* __restrict__ db2,
    float* __restrict__ ab1, float* __restrict__ ab2) {
  __shared__ float red[256];
  int o = blockIdx.x, t = threadIdx.x;
  if (o == 0) { ab1[t] = fmaxf(db1[t], 0.f); ab1[t + 256] = fmaxf(db1[t + 256], 0.f); }
  const float* wp = dw2 + (long)o * C2 * 5;
  float acc = 0.f;
  #pragma unroll
  for (int h = 0; h < 2; ++h) {
    int c = t + h * 256;
    const float* p = wp + c * 5;
    float wsum = p[0] + p[1] + p[2] + p[3] + p[4];
    acc = fmaf(wsum, fmaxf(db1[c], 0.f), acc);
  }
  red[t] = acc;
  __syncthreads();
  for (int off = 128; off; off >>= 1) {
    if (t < off) red[t] += red[t + off];
    __syncthreads();
  }
  if (t == 0) ab2[o] = fmaxf(red[0] + db2[o], 0.f);
}

// ---------------- prep B: cconst = tanh(db3 + sum_o (sum_j dw3[o][j]) * ab2[o]) ----
__global__ __launch_bounds__(256) void k_prep_c(const float* __restrict__ dw3,
    const float* __restrict__ db3, const float* __restrict__ ab2,
    float* __restrict__ cconst) {
  __shared__ float red[256];
  int t = threadIdx.x;
  float wsum3 = 0.f;
  #pragma unroll
  for (int j = 0; j < 7; ++j) wsum3 += dw3[t*7+j];
  red[t] = wsum3 * ab2[t];
  __syncthreads();
  for (int off = 128; off; off >>= 1) {
    if (t < off) red[t] += red[t + off];
    __syncthreads();
  }
  if (t == 0) cconst[0] = tanhf(red[0] + db3[0]);
}

// ---------------- encoder conv1 (k7,p3) at the 5 cols conv2 needs, as im2col ------
// X1[n][ic*5+jj] = h1[b][ic][768s+jj-2]  (0 if tcol<0: conv2 zero pad)
__global__ __launch_bounds__(256) void k_enc1(const float* __restrict__ audio,
    const float* __restrict__ ew1, const float* __restrict__ eb1,
    ushort* __restrict__ X1h, ushort* __restrict__ X1l) {
  int n = blockIdx.x, ic = threadIdx.x;
  int b = n >> 7, s = n & 127;
  const float* ap = audio + (long)b * T_IN;
  int base = HOP * s - 5;           // audio idx for window pos 0
  float a[11];
  #pragma unroll
  for (int w = 0; w < 11; ++w) {
    int ai = base + w;
    a[w] = (ai >= 0 && ai < T_IN) ? ap[ai] : 0.f;
  }
  float w1[7];
  #pragma unroll
  for (int j = 0; j < 7; ++j) w1[j] = ew1[ic*7+j];
  float b1 = eb1[ic];
  long off = (long)n * 1280 + ic * 5;
  #pragma unroll
  for (int jj = 0; jj < 5; ++jj) {
    int tcol = HOP * s + jj - 2;
    float v = 0.f;
    if (tcol >= 0) {
      float acc = b1;
      #pragma unroll
      for (int j = 0; j < 7; ++j) acc = fmaf(w1[j], a[jj + j], acc);
      v = fmaxf(acc, 0.f);
    }
    uint bi = __float_as_uint(v);
    X1h[off + jj] = (ushort)(bi >> 16);
    float r = v - __uint_as_float(bi & 0xffff0000u);
    X1l[off + jj] = (ushort)(__float_as_uint(r) >> 16);
  }
}

// ---------------- encoder conv2 as GEMM: h2c[n][oc] = relu(eb2 + ew2 . X1^T) ------
// A = ew2 fp32 [512][1280] (OTF split; layout [oc][ic*5+jj] matches X1's k),
// B = X1 splits [256][1280]; 3xBF16 MFMA, no-LDS 1-wave blocks, grid (16, 4)
__global__ __launch_bounds__(64) void gemm_enc2(const float* __restrict__ ew2,
    const ushort* __restrict__ X1h, const ushort* __restrict__ X1l,
    const float* __restrict__ eb2, float* __restrict__ h2c) {
  const int t = threadIdx.x;
  const int l15 = t & 15, quad = t >> 4;
  const int m0 = blockIdx.x * 32, n0 = blockIdx.y * 64;
  f32x4 acc[2][4] = {};
  const float*  aB = ew2 + (long)(m0 + l15) * 1280 + quad * 8;
  const ushort* bhB = X1h + (long)(n0 + l15) * 1280 + quad * 8;
  const ushort* blB = X1l + (long)(n0 + l15) * 1280 + quad * 8;
  for (int k0 = 0; k0 < 1280; k0 += 32) {
    short8 ah[2], al[2], bh[4], bl[4];
    #pragma unroll
    for (int f = 0; f < 2; ++f) {
      const float* ap = aB + (long)f * 16 * 1280 + k0;
      float4 x0 = *(const float4*)ap;
      float4 x1 = *(const float4*)(ap + 4);
      split8(x0, x1, ah[f], al[f]);
    }
    #pragma unroll
    for (int f = 0; f < 4; ++f) {
      bh[f] = *(const short8*)(bhB + (long)f * 16 * 1280 + k0);
      bl[f] = *(const short8*)(blB + (long)f * 16 * 1280 + k0);
    }
    #pragma unroll
    for (int i = 0; i < 2; ++i)
      #pragma unroll
      for (int j = 0; j < 4; ++j) {
        acc[i][j] = __builtin_amdgcn_mfma_f32_16x16x32_bf16(ah[i], bh[j], acc[i][j], 0, 0, 0);
        acc[i][j] = __builtin_amdgcn_mfma_f32_16x16x32_bf16(ah[i], bl[j], acc[i][j], 0, 0, 0);
        acc[i][j] = __builtin_amdgcn_mfma_f32_16x16x32_bf16(al[i], bh[j], acc[i][j], 0, 0, 0);
      }
  }
  #pragma unroll
  for (int i = 0; i < 2; ++i) {
    const int obase = m0 + i * 16 + quad * 4;
    float4 bias = *(const float4*)(eb2 + obase);
    #pragma unroll
    for (int j = 0; j < 4; ++j) {
      const int n = n0 + j * 16 + l15;
      float4 out;
      out.x = fmaxf(acc[i][j][0] + bias.x, 0.f);
      out.y = fmaxf(acc[i][j][1] + bias.y, 0.f);
      out.z = fmaxf(acc[i][j][2] + bias.z, 0.f);
      out.w = fmaxf(acc[i][j][3] + bias.w, 0.f);
      *(float4*)(h2c + (long)n * C2 + obase) = out;
    }
  }
}

// ---------------- im2col for conv3 (k3,p1), written as bf16 hi/lo split ----------
__global__ void k_h2x(const float* __restrict__ h2c, ushort* __restrict__ h2xh,
                      ushort* __restrict__ h2xl) {
  int idx = blockIdx.x * 256 + threadIdx.x;
  const int total = NN * 1536;
  for (; idx < total; idx += gridDim.x * 256) {
    int n = idx / 1536, r = idx - n * 1536;
    int ic = r / 3, j = r - ic * 3;
    int s2 = (n & 127) + j - 1;
    int b = n >> 7;
    float v = (s2 >= 0 && s2 < SS) ? h2c[(long)(b*SS + s2)*C2 + ic] : 0.f;
    uint bi = __float_as_uint(v);
    h2xh[idx] = (ushort)(bi >> 16);
    float rr = v - __uint_as_float(bi & 0xffff0000u);
    h2xl[idx] = (ushort)(__float_as_uint(rr) >> 16);
  }
}

// ---------------- S1: h3 = ew3 . h2x^T + eb3, 3xBF16 MFMA, no-LDS 1-wave blocks ----
__global__ __launch_bounds__(64) void gemm_h3(const float* __restrict__ A,
    const ushort* __restrict__ Bh, const ushort* __restrict__ Bl,
    const float* __restrict__ eb3, ushort* __restrict__ h3h, ushort* __restrict__ h3l) {
  const int t = threadIdx.x;
  const int l15 = t & 15, quad = t >> 4;
  const int m0 = blockIdx.x * 64, n0 = blockIdx.y * 64;
  f32x4 acc[4][4] = {};
  const float*  aB = A  + (long)(m0 + l15) * 1536 + quad * 8;
  const ushort* bhB = Bh + (long)(n0 + l15) * 1536 + quad * 8;
  const ushort* blB = Bl + (long)(n0 + l15) * 1536 + quad * 8;
  for (int k0 = 0; k0 < 1536; k0 += 32) {
    short8 ah[4], al[4], bh[4], bl[4];
    #pragma unroll
    for (int f = 0; f < 4; ++f) {
      const float* ap = aB + (long)f * 16 * 1536 + k0;
      float4 x0 = *(const float4*)ap;
      float4 x1 = *(const float4*)(ap + 4);
      split8(x0, x1, ah[f], al[f]);
      bh[f] = *(const short8*)(bhB + (long)f * 16 * 1536 + k0);
      bl[f] = *(const short8*)(blB + (long)f * 16 * 1536 + k0);
    }
    #pragma unroll
    for (int i = 0; i < 4; ++i)
      #pragma unroll
      for (int j = 0; j < 4; ++j) {
        acc[i][j] = __builtin_amdgcn_mfma_f32_16x16x32_bf16(ah[i], bh[j], acc[i][j], 0, 0, 0);
        acc[i][j] = __builtin_amdgcn_mfma_f32_16x16x32_bf16(ah[i], bl[j], acc[i][j], 0, 0, 0);
        acc[i][j] = __builtin_amdgcn_mfma_f32_16x16x32_bf16(al[i], bh[j], acc[i][j], 0, 0, 0);
      }
  }
  #pragma unroll
  for (int i = 0; i < 4; ++i) {
    const int mbase = m0 + i * 16 + quad * 4;
    float4 bias = *(const float4*)(eb3 + mbase);
    #pragma unroll
    for (int j = 0; j < 4; ++j) {
      const int n = n0 + j * 16 + l15;
      float v0 = acc[i][j][0] + bias.x;
      float v1 = acc[i][j][1] + bias.y;
      float v2 = acc[i][j][2] + bias.z;
      float v3 = acc[i][j][3] + bias.w;
      uint b0 = __float_as_uint(v0), b1 = __float_as_uint(v1);
      uint b2 = __float_as_uint(v2), b3 = __float_as_uint(v3);
      uint2 hp;
      hp.x = (b0 >> 16) | (b1 & 0xffff0000u);
      hp.y = (b2 >> 16) | (b3 & 0xffff0000u);
      float r0 = v0 - __uint_as_float(b0 & 0xffff0000u);
      float r1 = v1 - __uint_as_float(b1 & 0xffff0000u);
      float r2 = v2 - __uint_as_float(b2 & 0xffff0000u);
      float r3 = v3 - __uint_as_float(b3 & 0xffff0000u);
      uint2 lp;
      lp.x = (__float_as_uint(r0) >> 16) | (__float_as_uint(r1) & 0xffff0000u);
      lp.y = (__float_as_uint(r2) >> 16) | (__float_as_uint(r3) & 0xffff0000u);
      long off = (long)n * C3 + mbase;
      *(uint2*)(h3h + off) = hp;
      *(uint2*)(h3l + off) = lp;
    }
  }
}

// ---------------- S2: scores = cbn - 2*cb.h3^T, 3xBF16 MFMA, no-LDS 1-wave blocks --
__global__ __launch_bounds__(64) void gemm_scores(const float* __restrict__ cb,
    const ushort* __restrict__ h3h, const ushort* __restrict__ h3l,
    const float* __restrict__ cbn, float* __restrict__ scores) {
  const int t = threadIdx.x;
  const int l15 = t & 15, quad = t >> 4;
  const int m0 = blockIdx.x * 64, n0 = blockIdx.y * 64, z = blockIdx.z;
  f32x4 acc[4][4] = {};
  const float*  aB = cb + (long)z * VOC * DIMV + (long)(m0 + l15) * 512 + quad * 8;
  const ushort* bhB = h3h + (long)(n0 + l15) * C3 + z * 512 + quad * 8;
  const ushort* blB = h3l + (long)(n0 + l15) * C3 + z * 512 + quad * 8;
  for (int k0 = 0; k0 < 512; k0 += 32) {
    short8 ah[4], al[4], bh[4], bl[4];
    #pragma unroll
    for (int f = 0; f < 4; ++f) {
      const float* ap = aB + (long)f * 16 * 512 + k0;
      float4 x0 = *(const float4*)ap;
      float4 x1 = *(const float4*)(ap + 4);
      split8(x0, x1, ah[f], al[f]);
      bh[f] = *(const short8*)(bhB + (long)f * 16 * C3 + k0);
      bl[f] = *(const short8*)(blB + (long)f * 16 * C3 + k0);
    }
    #pragma unroll
    for (int i = 0; i < 4; ++i)
      #pragma unroll
      for (int j = 0; j < 4; ++j) {
        acc[i][j] = __builtin_amdgcn_mfma_f32_16x16x32_bf16(ah[i], bh[j], acc[i][j], 0, 0, 0);
        acc[i][j] = __builtin_amdgcn_mfma_f32_16x16x32_bf16(ah[i], bl[j], acc[i][j], 0, 0, 0);
        acc[i][j] = __builtin_amdgcn_mfma_f32_16x16x32_bf16(al[i], bh[j], acc[i][j], 0, 0, 0);
      }
  }
  #pragma unroll
  for (int i = 0; i < 4; ++i) {
    const int vbase = m0 + i * 16 + quad * 4;
    float4 cn = *(const float4*)(cbn + z * VOC + vbase);
    #pragma unroll
    for (int j = 0; j < 4; ++j) {
      const int n = n0 + j * 16 + l15;
      float4 out;
      out.x = cn.x - 2.f * acc[i][j][0];
      out.y = cn.y - 2.f * acc[i][j][1];
      out.z = cn.z - 2.f * acc[i][j][2];
      out.w = cn.w - 2.f * acc[i][j][3];
      *(float4*)(scores + ((long)z * NN + n) * VOC + vbase) = out;
    }
  }
}

// ---------------- argmin over 1024 codes, numpy tie-break (lowest v) ----------------
__global__ void k_argmin(const float* __restrict__ scores, int* __restrict__ codes) {
  int row = blockIdx.x;          // k*256+n
  int lane = threadIdx.x;        // 64
  const float* p = scores + (long)row * VOC;
  float best = 3.4e38f; int bi = 0;
  for (int i = 0; i < 16; ++i) {
    int v = i * 64 + lane;
    float x = p[v];
    if (x < best) { best = x; bi = v; }
  }
  for (int off = 32; off; off >>= 1) {
    float ob = __shfl_down(best, off);
    int oi = __shfl_down(bi, off);
    if (ob < best || (ob == best && oi < bi)) { best = ob; bi = oi; }
  }
  if (lane == 0) codes[row] = bi;
}

// ---------------- transpose+convert dw1 [7168][2560] fp32 -> dw1t [2560][7168] bf16 ----
__global__ __launch_bounds__(256) void k_dw1t(const float* __restrict__ dw1,
                                              ushort* __restrict__ dw1t) {
  __shared__ __align__(16) ushort T[64 * 72];   // [m][k] tile, pitch 72
  int t = threadIdx.x;
  int k0 = blockIdx.x * 64, m0 = blockIdx.y * 64;
  int kk = t >> 2, mj = (t & 3) * 16;
  const float* src = dw1 + (long)(k0 + kk) * 2560 + m0 + mj;
  float x[16];
  *(float4*)&x[0]  = *(const float4*)(src);
  *(float4*)&x[4]  = *(const float4*)(src + 4);
  *(float4*)&x[8]  = *(const float4*)(src + 8);
  *(float4*)&x[12] = *(const float4*)(src + 12);
  #pragma unroll
  for (int l = 0; l < 16; ++l)
    T[(mj + l) * 72 + kk] = f2bf(x[l]);
  __syncthreads();
  int mo = t >> 2, kc = (t & 3) * 16;
  uint4 u0 = *(const uint4*)&T[mo * 72 + kc];
  uint4 u1 = *(const uint4*)&T[mo * 72 + kc + 8];
  ushort* dst = dw1t + (long)(m0 + mo) * C3 + k0 + kc;
  *(uint4*)dst = u0;
  *(uint4*)(dst + 8) = u1;
}

// ---------------- gather q as bf16: qbf[n][k*512+d] = bf16(cb[k, code, d]) ----------
__global__ void k_gather_qbf(const float* __restrict__ cb, const int* __restrict__ codes,
                             ushort* __restrict__ qbf) {
  int idx = blockIdx.x * 256 + threadIdx.x;      // pair index
  const int total = NN * C3 / 2;                 // 917504
  if (idx >= total) return;
  int n = idx / 3584, rr = idx - n * 3584;       // rr = k*256 + dp
  int k = rr >> 8, dp = rr & 255;
  int code = codes[k * NN + n];
  const float* s = cb + ((long)(k * VOC + code)) * DIMV + dp * 2;
  uint lo = f2bf(s[0]), hi = f2bf(s[1]);
  ((uint*)qbf)[idx] = lo | (hi << 16);
}

// ---------------- decoder convT GEMM via MFMA bf16 ----------------
// No-LDS direct bf16 fragment loads, zero barriers in the K-loop. 4 waves per
// block each own a disjoint K-quarter (1792) of the same 64x64 output tile;
// one-shot LDS tree-reduce at the end.
__global__ __launch_bounds__(256) void gemm_a1_mfma(const ushort* __restrict__ dw1t,
    const ushort* __restrict__ qbf, float* __restrict__ a1raw) {
  // red[wave][chunk=i*4+j][lane] as float4 -> 4*16*64*4 floats = 64 KB
  __shared__ __align__(16) float red[4 * 4096];
  const int tid = threadIdx.x;
  const int w = tid >> 6, lane = tid & 63;
  const int l15 = lane & 15, quad = lane >> 4;
  const int m0 = blockIdx.x * 64, n0 = blockIdx.y * 64;
  const int kbase = w * 1792;                 // disjoint K-quarter per wave
  f32x4 acc[4][4] = {};
  const ushort* aB = dw1t + (long)(m0 + l15) * C3 + kbase + quad * 8;
  const ushort* bB = qbf  + (long)(n0 + l15) * C3 + kbase + quad * 8;
  #pragma unroll 2
  for (int k0 = 0; k0 < 1792; k0 += 32) {
    short8 ah[4], bh[4];
    #pragma unroll
    for (int f = 0; f < 4; ++f) {
      ah[f] = *(const short8*)(aB + (long)f * 16 * C3 + k0);
      bh[f] = *(const short8*)(bB + (long)f * 16 * C3 + k0);
    }
    #pragma unroll
    for (int i = 0; i < 4; ++i)
      #pragma unroll
      for (int j = 0; j < 4; ++j)
        acc[i][j] = __builtin_amdgcn_mfma_f32_16x16x32_bf16(ah[i], bh[j], acc[i][j], 0, 0, 0);
  }
  // stash partials: region w, chunk (i*4+j), lane-contiguous float4 (conflict-free)
  #pragma unroll
  for (int i = 0; i < 4; ++i)
    #pragma unroll
    for (int j = 0; j < 4; ++j)
      *(float4*)&red[w * 4096 + (i * 4 + j) * 256 + lane * 4] = *(float4*)&acc[i][j];
  __syncthreads();
  // wave w reduces the 4 K-partials for row-block i=w and scatters to a1raw
  #pragma unroll
  for (int j = 0; j < 4; ++j) {
    float4 s = *(const float4*)&red[(w * 4 + j) * 256 + lane * 4];
    #pragma unroll
    for (int r = 1; r < 4; ++r) {
      float4 tt = *(const float4*)&red[r * 4096 + (w * 4 + j) * 256 + lane * 4];
      s.x += tt.x; s.y += tt.y; s.z += tt.z; s.w += tt.w;
    }
    const int n = n0 + j * 16 + l15;
    const int mb = m0 + w * 16 + quad * 4;
    float v[4] = {s.x, s.y, s.z, s.w};
    #pragma unroll
    for (int reg = 0; reg < 4; ++reg) {
      int m = mb + reg;
      int c = m / 5, jj = m - c * 5;
      a1raw[((long)(n * 5 + jj)) * C2 + c] = v[reg];
    }
  }
}

// ---------------- k_x2: build conv2 im2col X (bf16 hi/lo) from a1raw/ab1 ----------
__global__ void k_x2(const float* __restrict__ a1raw, const float* __restrict__ ab1g,
                     const float* __restrict__ db1, ushort* __restrict__ Xh,
                     ushort* __restrict__ Xl) {
  int idx = blockIdx.x * 256 + threadIdx.x;
  const int total = 2304 * 2560;
  for (; idx < total; idx += gridDim.x * 256) {
    int nu = idx / 2560, ck = idx - nu * 2560;
    int n = nu / 9, u = nu - n * 9;
    int c = ck / 5, jj = ck - c * 5;
    int w = u + jj;
    int s = n & 127;
    int tc = HOP * s - 6 + w;
    float v;
    if (tc < 0 || tc > TOUT - 1) v = 0.f;
    else if (w >= 4 && w <= 8)
      v = fmaxf(db1[c] + a1raw[((long)(n * 5 + (w - 4))) * C2 + c], 0.f);
    else v = ab1g[c];
    uint bi = __float_as_uint(v);
    Xh[idx] = (ushort)(bi >> 16);
    float rr = v - __uint_as_float(bi & 0xffff0000u);
    Xl[idx] = (ushort)(__float_as_uint(rr) >> 16);
  }
}

// ---------------- decoder conv2 as GEMM: a2act = relu(db2 + dw2 . X^T) ----------
// Rewritten like gemm_a1_mfma: 4-wave blocks, disjoint K-quarter (640) per wave,
// barrier-free K-loop with direct loads (A fp32 split OTF), LDS reduce epilogue.
// Old: 64-thread 1-wave blocks, 80 serial K-iters -> latency-bound (83 us,
// Occupancy 1.5%, MfmaUtil 4%).
__global__ __launch_bounds__(256) void gemm_dec2(const float* __restrict__ dw2,
    const ushort* __restrict__ Xh, const ushort* __restrict__ Xl,
    const float* __restrict__ db2, float* __restrict__ a2act) {
  __shared__ __align__(16) float red[4 * 4096];   // 64 KB
  const int tid = threadIdx.x;
  const int w = tid >> 6, lane = tid & 63;
  const int l15 = lane & 15, quad = lane >> 4;
  const int m0 = blockIdx.x * 64, n0 = blockIdx.y * 64;
  const int kbase = w * 640;                  // disjoint K-quarter per wave
  f32x4 acc[4][4] = {};
  const float*  aB = dw2 + (long)(m0 + l15) * 2560 + kbase + quad * 8;
  const ushort* bhB = Xh + (long)(n0 + l15) * 2560 + kbase + quad * 8;
  const ushort* blB = Xl + (long)(n0 + l15) * 2560 + kbase + quad * 8;
  for (int k0 = 0; k0 < 640; k0 += 32) {
    short8 ah[4], al[4], bh[4], bl[4];
    #pragma unroll
    for (int f = 0; f < 4; ++f) {
      const float* ap = aB + (long)f * 16 * 2560 + k0;
      float4 x0 = *(const float4*)ap;
      float4 x1 = *(const float4*)(ap + 4);
      split8(x0, x1, ah[f], al[f]);
      bh[f] = *(const short8*)(bhB + (long)f * 16 * 2560 + k0);
      bl[f] = *(const short8*)(blB + (long)f * 16 * 2560 + k0);
    }
    #pragma unroll
    for (int i = 0; i < 4; ++i)
      #pragma unroll
      for (int j = 0; j < 4; ++j) {
        acc[i][j] = __builtin_amdgcn_mfma_f32_16x16x32_bf16(ah[i], bh[j], acc[i][j], 0, 0, 0);
        acc[i][j] = __builtin_amdgcn_mfma_f32_16x16x32_bf16(ah[i], bl[j], acc[i][j], 0, 0, 0);
        acc[i][j] = __builtin_amdgcn_mfma_f32_16x16x32_bf16(al[i], bh[j], acc[i][j], 0, 0, 0);
      }
  }
  // stash partials: region w, chunk (i*4+j), lane-contiguous float4 (2-way = free)
  #pragma unroll
  for (int i = 0; i < 4; ++i)
    #pragma unroll
    for (int j = 0; j < 4; ++j)
      *(float4*)&red[w * 4096 + (i * 4 + j) * 256 + lane * 4] = *(float4*)&acc[i][j];
  __syncthreads();
  // wave w reduces the 4 K-partials for row-block i=w, applies bias+relu, stores
  const int mb = m0 + w * 16 + quad * 4;
  float4 bias = *(const float4*)(db2 + mb);
  #pragma unroll
  for (int j = 0; j < 4; ++j) {
    float4 s = *(const float4*)&red[(w * 4 + j) * 256 + lane * 4];
    #pragma unroll
    for (int r = 1; r < 4; ++r) {
      float4 tt = *(const float4*)&red[r * 4096 + (w * 4 + j) * 256 + lane * 4];
      s.x += tt.x; s.y += tt.y; s.z += tt.z; s.w += tt.w;
    }
    const int nu = n0 + j * 16 + l15;
    float4 out;
    out.x = fmaxf(s.x + bias.x, 0.f);
    out.y = fmaxf(s.y + bias.y, 0.f);
    out.z = fmaxf(s.z + bias.z, 0.f);
    out.w = fmaxf(s.w + bias.w, 0.f);
    *(float4*)(a2act + (long)nu * C1 + mb) = out;
  }
}

// ---------------- fill output with the constant tanh value ----------------
__global__ void k_fill(float* __restrict__ outp, const float* __restrict__ cconst) {
  float v = cconst[0];
  int idx = blockIdx.x * 256 + threadIdx.x;
  const int total = NBATCH * TOUT;
  for (; idx < total; idx += gridDim.x * 256) outp[idx] = v;
}

// ---------------- decoder conv3+tanh on 15 active cols per (b,s) ----------------
__global__ __launch_bounds__(256) void k_dec3(const float* __restrict__ a2act,
    const float* __restrict__ ab2g, const float* __restrict__ dw3,
    const float* __restrict__ db3, float* __restrict__ outp) {
  __shared__ float sa2[9 * C1];
  __shared__ float sb[C1];
  int n = blockIdx.x;
  int s = n & 127, b = n >> 7;
  int t = threadIdx.x;
  for (int i = t; i < 9 * C1; i += 256) sa2[i] = a2act[(long)n * 9 * C1 + i];
  sb[t] = ab2g[t];
  __syncthreads();
  int wv = t >> 6, lane = t & 63;
  float b3 = db3[0];
  for (int w15 = wv; w15 < 15; w15 += 4) {
    int tc = HOP * s - 7 + w15;
    if (tc < 0 || tc > TOUT - 1) continue;
    float part = 0.f;
    for (int cc = lane; cc < C1; cc += 64) {
      #pragma unroll
      for (int j = 0; j < 7; ++j) {
        int wcol = tc + j - 3;
        float x;
        if (wcol < 0 || wcol > TOUT - 1) x = 0.f;
        else {
          int du = wcol - (HOP * s - 4);
          x = (du >= 0 && du <= 8) ? sa2[du * C1 + cc] : sb[cc];
        }
        part = fmaf(dw3[cc*7+j], x, part);
      }
    }
    for (int off = 32; off; off >>= 1) part += __shfl_down(part, off);
    if (lane == 0) outp[(long)b * TOUT + tc] = tanhf(part + b3);
  }
}

extern "C" void kernel_launch(void* const* d_in, const int* in_sizes, int n_in,
                              void* d_out, int out_size, void* d_ws, size_t ws_size,
                              hipStream_t stream) {
  const float* audio = (const float*)d_in[0];
  const float* cb    = (const float*)d_in[1];
  const float* ew1   = (const float*)d_in[2];
  const float* eb1   = (const float*)d_in[3];
  const float* ew2   = (const float*)d_in[4];
  const float* eb2   = (const float*)d_in[5];
  const float* ew3   = (const float*)d_in[6];
  const float* eb3   = (const float*)d_in[7];
  const float* dw1   = (const float*)d_in[8];
  const float* db1   = (const float*)d_in[9];
  const float* dw2   = (const float*)d_in[10];
  const float* db2   = (const float*)d_in[11];
  const float* dw3   = (const float*)d_in[12];
  const float* db3   = (const float*)d_in[13];
  float* outp = (float*)d_out;
  float* ws = (float*)d_ws;

  float*  cbn    = ws + OFF_CBN;
  float*  ab1    = ws + OFF_AB1;
  float*  ab2    = ws + OFF_AB2;
  float*  cconst = ws + OFF_CCONST;
  float*  h2c    = ws + OFF_H2C;
  ushort* h2xh   = (ushort*)(ws + OFF_H2XH);
  ushort* h2xl   = (ushort*)(ws + OFF_H2XL);
  ushort* h3h    = (ushort*)(ws + OFF_H3H);
  ushort* h3l    = (ushort*)(ws + OFF_H3L);
  float*  scores = ws + OFF_SCORES;
  ushort* X1h    = (ushort*)(ws + OFF_X1H);
  ushort* X1l    = (ushort*)(ws + OFF_X1L);
  ushort* dw1t   = (ushort*)(ws + OFF_DW1T);
  ushort* Xh     = (ushort*)(ws + OFF_XH);
  ushort* Xl     = (ushort*)(ws + OFF_XL);
  int*    codes  = (int*)(ws + OFF_CODES);
  ushort* qbf    = (ushort*)(ws + OFF_QBF);
  float*  a1raw  = ws + OFF_A1RAW;
  float*  a2act  = ws + OFF_A2ACT;

  k_cbn<<<3584, 256, 0, stream>>>(cb, cbn);
  k_prep_ab2<<<C1, 256, 0, stream>>>(db1, dw2, db2, ab1, ab2);
  k_prep_c<<<1, 256, 0, stream>>>(dw3, db3, ab2, cconst);
  k_enc1<<<NN, 256, 0, stream>>>(audio, ew1, eb1, X1h, X1l);
  gemm_enc2<<<dim3(16, 4), 64, 0, stream>>>(ew2, X1h, X1l, eb2, h2c);
  k_h2x<<<384, 256, 0, stream>>>(h2c, h2xh, h2xl);
  gemm_h3<<<dim3(112, 4), 64, 0, stream>>>(ew3, h2xh, h2xl, eb3, h3h, h3l);
  // gemm_scores writes over X1h/X1l (dead after gemm_enc2) — stream-ordered
  gemm_scores<<<dim3(16, 4, 14), 64, 0, stream>>>(cb, h3h, h3l, cbn, scores);
  k_argmin<<<NCBK * NN, 64, 0, stream>>>(scores, codes);
  // dw1t overlaps h3h/h3l/scores memory: must launch AFTER k_argmin (stream-ordered)
  k_dw1t<<<dim3(112, 40), 256, 0, stream>>>(dw1, dw1t);
  k_gather_qbf<<<3584, 256, 0, stream>>>(cb, codes, qbf);
  gemm_a1_mfma<<<dim3(40, 4), 256, 0, stream>>>(dw1t, qbf, a1raw);
  // Xh/Xl overlap dw1t memory: must launch AFTER gemm_a1_mfma (stream-ordered)
  k_x2<<<4096, 256, 0, stream>>>(a1raw, ab1, db1, Xh, Xl);
  gemm_dec2<<<dim3(4, 36), 256, 0, stream>>>(dw2, Xh, Xl, db2, a2act);
  k_fill<<<256, 256, 0, stream>>>(outp, cconst);
  k_dec3<<<NN, 256, 0, stream>>>(a2act, ab2, dw3, db3, outp);
}

// Round 3
// 464.968 us; speedup vs baseline: 1.1907x; 1.0332x over previous
//
#include <hip/hip_runtime.h>
#include <hip/hip_bf16.h>
#include <math.h>

#define T_IN 98304
#define SS 128
#define NBATCH 2
#define NN 256          // NBATCH*SS
#define C1 256
#define C2 512
#define C3 7168
#define NCBK 14
#define DIMV 512
#define VOC 1024
#define TOUT 97537
#define HOP 768

// ws layout (float offsets)
#define OFF_CBN    0L          // 14336
#define OFF_AB1    14336L      // 512
#define OFF_AB2    14848L      // 256
#define OFF_CCONST 15104L      // 16
#define OFF_H2C    15120L      // 131072   (n*512+ic), n=b*128+s
#define OFF_H2XH   146192L     // 196608 fl (ushort [256][1536] bf16-hi)
#define OFF_H2XL   342800L     // 196608 fl (bf16-lo)
#define OFF_H3H    539408L     // 917504 fl (ushort [256][7168] bf16-hi)
#define OFF_H3L    1456912L    // 917504 fl
#define OFF_SCORES 2374416L    // 3670016  ((k*256+n)*1024 + v)
// X1h/X1l (bf16 [256][1280] = 163840 fl each) OVERLAP scores region: X1 is dead
// before gemm_scores writes scores (same stream serializes).
#define OFF_X1H    2374416L    // ends 2538256
#define OFF_X1L    2538256L    // ends 2702096
// dw1t (bf16 [2560][7168] = 9175040 fl) OVERLAPS h3h/h3l/scores: all dead
// before k_dw1t runs (launched after k_argmin; same stream serializes).
#define OFF_DW1T   539408L     // ends 9714448
// Xh/Xl (bf16 [2304][2560] each = 2949120 fl each) OVERLAP dw1t: dw1t is dead
// after gemm_a1_mfma; k_x2 launches after it (same stream serializes).
#define OFF_XH     539408L     // ends 3488528
#define OFF_XL     3488528L    // ends 6437648
#define OFF_CODES  9714448L    // 3584 ints
#define OFF_QBF    9718032L    // 917504 fl (bf16 [256][7168])
#define OFF_A1RAW  10635536L   // 655360   ((n*5+j)*512 + c)  pre-bias/relu
#define OFF_A2ACT  11290896L   // 589824   ((n*9+u)*256 + o)  post-relu
// total 11880720 floats = 47.5 MB

typedef __attribute__((ext_vector_type(8))) short short8;
typedef __attribute__((ext_vector_type(4))) float f32x4;

static __device__ inline ushort f2bf(float x) {
  __hip_bfloat16 h = __float2bfloat16(x);
  return *reinterpret_cast<ushort*>(&h);
}

// exact 2-term split: x = hi + lo + O(2^-16 |x|); truncation split, residual exact
static __device__ inline void split8(const float4 x0, const float4 x1,
                                     short8& h, short8& l) {
  float xs[8] = {x0.x, x0.y, x0.z, x0.w, x1.x, x1.y, x1.z, x1.w};
  #pragma unroll
  for (int e = 0; e < 8; ++e) {
    uint b = __float_as_uint(xs[e]);
    h[e] = (short)(b >> 16);
    float r = xs[e] - __uint_as_float(b & 0xffff0000u);
    l[e] = (short)(__float_as_uint(r) >> 16);
  }
}

// ---------------- prep: codebook norms ----------------
__global__ void k_cbn(const float* __restrict__ cb, float* __restrict__ cbn) {
  int row = blockIdx.x * 4 + (threadIdx.x >> 6);
  int lane = threadIdx.x & 63;
  const float* p = cb + (long)row * DIMV;
  float s = 0.f;
  for (int d = lane; d < DIMV; d += 64) { float x = p[d]; s += x * x; }
  for (int off = 32; off; off >>= 1) s += __shfl_down(s, off);
  if (lane == 0) cbn[row] = s;
}

// ---------------- prep A: ab1 = relu(db1); ab2[o] = relu(db2[o]+sum_c W(o,c)*ab1[c])
__global__ __launch_bounds__(256) void k_prep_ab2(const float* __restrict__ db1,
    const float* __restrict__ dw2, const float* __restrict__ db2,
    float* __restrict__ ab1, float* __restrict__ ab2) {
  __shared__ float red[256];
  int o = blockIdx.x, t = threadIdx.x;
  if (o == 0) { ab1[t] = fmaxf(db1[t], 0.f); ab1[t + 256] = fmaxf(db1[t + 256], 0.f); }
  const float* wp = dw2 + (long)o * C2 * 5;
  float acc = 0.f;
  #pragma unroll
  for (int h = 0; h < 2; ++h) {
    int c = t + h * 256;
    const float* p = wp + c * 5;
    float wsum = p[0] + p[1] + p[2] + p[3] + p[4];
    acc = fmaf(wsum, fmaxf(db1[c], 0.f), acc);
  }
  red[t] = acc;
  __syncthreads();
  for (int off = 128; off; off >>= 1) {
    if (t < off) red[t] += red[t + off];
    __syncthreads();
  }
  if (t == 0) ab2[o] = fmaxf(red[0] + db2[o], 0.f);
}

// ---------------- prep B: cconst = tanh(db3 + sum_o (sum_j dw3[o][j]) * ab2[o]) ----
__global__ __launch_bounds__(256) void k_prep_c(const float* __restrict__ dw3,
    const float* __restrict__ db3, const float* __restrict__ ab2,
    float* __restrict__ cconst) {
  __shared__ float red[256];
  int t = threadIdx.x;
  float wsum3 = 0.f;
  #pragma unroll
  for (int j = 0; j < 7; ++j) wsum3 += dw3[t*7+j];
  red[t] = wsum3 * ab2[t];
  __syncthreads();
  for (int off = 128; off; off >>= 1) {
    if (t < off) red[t] += red[t + off];
    __syncthreads();
  }
  if (t == 0) cconst[0] = tanhf(red[0] + db3[0]);
}

// ---------------- encoder conv1 (k7,p3) at the 5 cols conv2 needs, as im2col ------
// X1[n][ic*5+jj] = h1[b][ic][768s+jj-2]  (0 if tcol<0: conv2 zero pad)
__global__ __launch_bounds__(256) void k_enc1(const float* __restrict__ audio,
    const float* __restrict__ ew1, const float* __restrict__ eb1,
    ushort* __restrict__ X1h, ushort* __restrict__ X1l) {
  int n = blockIdx.x, ic = threadIdx.x;
  int b = n >> 7, s = n & 127;
  const float* ap = audio + (long)b * T_IN;
  int base = HOP * s - 5;           // audio idx for window pos 0
  float a[11];
  #pragma unroll
  for (int w = 0; w < 11; ++w) {
    int ai = base + w;
    a[w] = (ai >= 0 && ai < T_IN) ? ap[ai] : 0.f;
  }
  float w1[7];
  #pragma unroll
  for (int j = 0; j < 7; ++j) w1[j] = ew1[ic*7+j];
  float b1 = eb1[ic];
  long off = (long)n * 1280 + ic * 5;
  #pragma unroll
  for (int jj = 0; jj < 5; ++jj) {
    int tcol = HOP * s + jj - 2;
    float v = 0.f;
    if (tcol >= 0) {
      float acc = b1;
      #pragma unroll
      for (int j = 0; j < 7; ++j) acc = fmaf(w1[j], a[jj + j], acc);
      v = fmaxf(acc, 0.f);
    }
    uint bi = __float_as_uint(v);
    X1h[off + jj] = (ushort)(bi >> 16);
    float r = v - __uint_as_float(bi & 0xffff0000u);
    X1l[off + jj] = (ushort)(__float_as_uint(r) >> 16);
  }
}

// ---------------- encoder conv2 as GEMM: h2c[n][oc] = relu(eb2 + ew2 . X1^T) ------
// A = ew2 fp32 [512][1280] (OTF split; layout [oc][ic*5+jj] matches X1's k),
// B = X1 splits [256][1280]; 3xBF16 MFMA, no-LDS 1-wave blocks, grid (16, 4)
__global__ __launch_bounds__(64) void gemm_enc2(const float* __restrict__ ew2,
    const ushort* __restrict__ X1h, const ushort* __restrict__ X1l,
    const float* __restrict__ eb2, float* __restrict__ h2c) {
  const int t = threadIdx.x;
  const int l15 = t & 15, quad = t >> 4;
  const int m0 = blockIdx.x * 32, n0 = blockIdx.y * 64;
  f32x4 acc[2][4] = {};
  const float*  aB = ew2 + (long)(m0 + l15) * 1280 + quad * 8;
  const ushort* bhB = X1h + (long)(n0 + l15) * 1280 + quad * 8;
  const ushort* blB = X1l + (long)(n0 + l15) * 1280 + quad * 8;
  for (int k0 = 0; k0 < 1280; k0 += 32) {
    short8 ah[2], al[2], bh[4], bl[4];
    #pragma unroll
    for (int f = 0; f < 2; ++f) {
      const float* ap = aB + (long)f * 16 * 1280 + k0;
      float4 x0 = *(const float4*)ap;
      float4 x1 = *(const float4*)(ap + 4);
      split8(x0, x1, ah[f], al[f]);
    }
    #pragma unroll
    for (int f = 0; f < 4; ++f) {
      bh[f] = *(const short8*)(bhB + (long)f * 16 * 1280 + k0);
      bl[f] = *(const short8*)(blB + (long)f * 16 * 1280 + k0);
    }
    #pragma unroll
    for (int i = 0; i < 2; ++i)
      #pragma unroll
      for (int j = 0; j < 4; ++j) {
        acc[i][j] = __builtin_amdgcn_mfma_f32_16x16x32_bf16(ah[i], bh[j], acc[i][j], 0, 0, 0);
        acc[i][j] = __builtin_amdgcn_mfma_f32_16x16x32_bf16(ah[i], bl[j], acc[i][j], 0, 0, 0);
        acc[i][j] = __builtin_amdgcn_mfma_f32_16x16x32_bf16(al[i], bh[j], acc[i][j], 0, 0, 0);
      }
  }
  #pragma unroll
  for (int i = 0; i < 2; ++i) {
    const int obase = m0 + i * 16 + quad * 4;
    float4 bias = *(const float4*)(eb2 + obase);
    #pragma unroll
    for (int j = 0; j < 4; ++j) {
      const int n = n0 + j * 16 + l15;
      float4 out;
      out.x = fmaxf(acc[i][j][0] + bias.x, 0.f);
      out.y = fmaxf(acc[i][j][1] + bias.y, 0.f);
      out.z = fmaxf(acc[i][j][2] + bias.z, 0.f);
      out.w = fmaxf(acc[i][j][3] + bias.w, 0.f);
      *(float4*)(h2c + (long)n * C2 + obase) = out;
    }
  }
}

// ---------------- im2col for conv3 (k3,p1), written as bf16 hi/lo split ----------
__global__ void k_h2x(const float* __restrict__ h2c, ushort* __restrict__ h2xh,
                      ushort* __restrict__ h2xl) {
  int idx = blockIdx.x * 256 + threadIdx.x;
  const int total = NN * 1536;
  for (; idx < total; idx += gridDim.x * 256) {
    int n = idx / 1536, r = idx - n * 1536;
    int ic = r / 3, j = r - ic * 3;
    int s2 = (n & 127) + j - 1;
    int b = n >> 7;
    float v = (s2 >= 0 && s2 < SS) ? h2c[(long)(b*SS + s2)*C2 + ic] : 0.f;
    uint bi = __float_as_uint(v);
    h2xh[idx] = (ushort)(bi >> 16);
    float rr = v - __uint_as_float(bi & 0xffff0000u);
    h2xl[idx] = (ushort)(__float_as_uint(rr) >> 16);
  }
}

// ---------------- S1: h3 = ew3 . h2x^T + eb3 ----------------
// 4-wave blocks, disjoint K-quarter (384) per wave, barrier-free K-loop,
// LDS reduce epilogue. Old: 1-wave blocks, 48 serial K-iters -> latency-bound
// (77 us, Occupancy 4.6%, MfmaUtil 8%).
__global__ __launch_bounds__(256) void gemm_h3(const float* __restrict__ A,
    const ushort* __restrict__ Bh, const ushort* __restrict__ Bl,
    const float* __restrict__ eb3, ushort* __restrict__ h3h, ushort* __restrict__ h3l) {
  __shared__ __align__(16) float red[4 * 4096];   // 64 KB
  const int tid = threadIdx.x;
  const int w = tid >> 6, lane = tid & 63;
  const int l15 = lane & 15, quad = lane >> 4;
  const int m0 = blockIdx.x * 64, n0 = blockIdx.y * 64;
  const int kbase = w * 384;                  // disjoint K-quarter per wave
  f32x4 acc[4][4] = {};
  const float*  aB = A  + (long)(m0 + l15) * 1536 + kbase + quad * 8;
  const ushort* bhB = Bh + (long)(n0 + l15) * 1536 + kbase + quad * 8;
  const ushort* blB = Bl + (long)(n0 + l15) * 1536 + kbase + quad * 8;
  for (int k0 = 0; k0 < 384; k0 += 32) {
    short8 ah[4], al[4], bh[4], bl[4];
    #pragma unroll
    for (int f = 0; f < 4; ++f) {
      const float* ap = aB + (long)f * 16 * 1536 + k0;
      float4 x0 = *(const float4*)ap;
      float4 x1 = *(const float4*)(ap + 4);
      split8(x0, x1, ah[f], al[f]);
      bh[f] = *(const short8*)(bhB + (long)f * 16 * 1536 + k0);
      bl[f] = *(const short8*)(blB + (long)f * 16 * 1536 + k0);
    }
    #pragma unroll
    for (int i = 0; i < 4; ++i)
      #pragma unroll
      for (int j = 0; j < 4; ++j) {
        acc[i][j] = __builtin_amdgcn_mfma_f32_16x16x32_bf16(ah[i], bh[j], acc[i][j], 0, 0, 0);
        acc[i][j] = __builtin_amdgcn_mfma_f32_16x16x32_bf16(ah[i], bl[j], acc[i][j], 0, 0, 0);
        acc[i][j] = __builtin_amdgcn_mfma_f32_16x16x32_bf16(al[i], bh[j], acc[i][j], 0, 0, 0);
      }
  }
  // stash partials: region w, chunk (i*4+j), lane-contiguous float4 (2-way = free)
  #pragma unroll
  for (int i = 0; i < 4; ++i)
    #pragma unroll
    for (int j = 0; j < 4; ++j)
      *(float4*)&red[w * 4096 + (i * 4 + j) * 256 + lane * 4] = *(float4*)&acc[i][j];
  __syncthreads();
  // wave w reduces the 4 K-partials for row-block i=w, adds bias, packs hi/lo
  const int mbase = m0 + w * 16 + quad * 4;
  float4 bias = *(const float4*)(eb3 + mbase);
  #pragma unroll
  for (int j = 0; j < 4; ++j) {
    float4 s = *(const float4*)&red[(w * 4 + j) * 256 + lane * 4];
    #pragma unroll
    for (int r = 1; r < 4; ++r) {
      float4 tt = *(const float4*)&red[r * 4096 + (w * 4 + j) * 256 + lane * 4];
      s.x += tt.x; s.y += tt.y; s.z += tt.z; s.w += tt.w;
    }
    const int n = n0 + j * 16 + l15;
    float v0 = s.x + bias.x;
    float v1 = s.y + bias.y;
    float v2 = s.z + bias.z;
    float v3 = s.w + bias.w;
    uint b0 = __float_as_uint(v0), b1 = __float_as_uint(v1);
    uint b2 = __float_as_uint(v2), b3 = __float_as_uint(v3);
    uint2 hp;
    hp.x = (b0 >> 16) | (b1 & 0xffff0000u);
    hp.y = (b2 >> 16) | (b3 & 0xffff0000u);
    float r0 = v0 - __uint_as_float(b0 & 0xffff0000u);
    float r1 = v1 - __uint_as_float(b1 & 0xffff0000u);
    float r2 = v2 - __uint_as_float(b2 & 0xffff0000u);
    float r3 = v3 - __uint_as_float(b3 & 0xffff0000u);
    uint2 lp;
    lp.x = (__float_as_uint(r0) >> 16) | (__float_as_uint(r1) & 0xffff0000u);
    lp.y = (__float_as_uint(r2) >> 16) | (__float_as_uint(r3) & 0xffff0000u);
    long off = (long)n * C3 + mbase;
    *(uint2*)(h3h + off) = hp;
    *(uint2*)(h3l + off) = lp;
  }
}

// ---------------- S2: scores = cbn - 2*cb.h3^T ----------------
// 4-wave blocks, disjoint K-quarter (128) per wave, barrier-free K-loop,
// LDS reduce epilogue (same transform as gemm_h3/gemm_dec2).
__global__ __launch_bounds__(256) void gemm_scores(const float* __restrict__ cb,
    const ushort* __restrict__ h3h, const ushort* __restrict__ h3l,
    const float* __restrict__ cbn, float* __restrict__ scores) {
  __shared__ __align__(16) float red[4 * 4096];   // 64 KB
  const int tid = threadIdx.x;
  const int w = tid >> 6, lane = tid & 63;
  const int l15 = lane & 15, quad = lane >> 4;
  const int m0 = blockIdx.x * 64, n0 = blockIdx.y * 64, z = blockIdx.z;
  const int kbase = w * 128;                  // disjoint K-quarter per wave
  f32x4 acc[4][4] = {};
  const float*  aB = cb + (long)z * VOC * DIMV + (long)(m0 + l15) * 512 + kbase + quad * 8;
  const ushort* bhB = h3h + (long)(n0 + l15) * C3 + z * 512 + kbase + quad * 8;
  const ushort* blB = h3l + (long)(n0 + l15) * C3 + z * 512 + kbase + quad * 8;
  for (int k0 = 0; k0 < 128; k0 += 32) {
    short8 ah[4], al[4], bh[4], bl[4];
    #pragma unroll
    for (int f = 0; f < 4; ++f) {
      const float* ap = aB + (long)f * 16 * 512 + k0;
      float4 x0 = *(const float4*)ap;
      float4 x1 = *(const float4*)(ap + 4);
      split8(x0, x1, ah[f], al[f]);
      bh[f] = *(const short8*)(bhB + (long)f * 16 * C3 + k0);
      bl[f] = *(const short8*)(blB + (long)f * 16 * C3 + k0);
    }
    #pragma unroll
    for (int i = 0; i < 4; ++i)
      #pragma unroll
      for (int j = 0; j < 4; ++j) {
        acc[i][j] = __builtin_amdgcn_mfma_f32_16x16x32_bf16(ah[i], bh[j], acc[i][j], 0, 0, 0);
        acc[i][j] = __builtin_amdgcn_mfma_f32_16x16x32_bf16(ah[i], bl[j], acc[i][j], 0, 0, 0);
        acc[i][j] = __builtin_amdgcn_mfma_f32_16x16x32_bf16(al[i], bh[j], acc[i][j], 0, 0, 0);
      }
  }
  // stash partials
  #pragma unroll
  for (int i = 0; i < 4; ++i)
    #pragma unroll
    for (int j = 0; j < 4; ++j)
      *(float4*)&red[w * 4096 + (i * 4 + j) * 256 + lane * 4] = *(float4*)&acc[i][j];
  __syncthreads();
  // wave w reduces the 4 K-partials for row-block i=w, applies cbn - 2*acc
  const int vbase = m0 + w * 16 + quad * 4;
  float4 cn = *(const float4*)(cbn + z * VOC + vbase);
  #pragma unroll
  for (int j = 0; j < 4; ++j) {
    float4 s = *(const float4*)&red[(w * 4 + j) * 256 + lane * 4];
    #pragma unroll
    for (int r = 1; r < 4; ++r) {
      float4 tt = *(const float4*)&red[r * 4096 + (w * 4 + j) * 256 + lane * 4];
      s.x += tt.x; s.y += tt.y; s.z += tt.z; s.w += tt.w;
    }
    const int n = n0 + j * 16 + l15;
    float4 out;
    out.x = cn.x - 2.f * s.x;
    out.y = cn.y - 2.f * s.y;
    out.z = cn.z - 2.f * s.z;
    out.w = cn.w - 2.f * s.w;
    *(float4*)(scores + ((long)z * NN + n) * VOC + vbase) = out;
  }
}

// ---------------- argmin over 1024 codes, numpy tie-break (lowest v) ----------------
__global__ void k_argmin(const float* __restrict__ scores, int* __restrict__ codes) {
  int row = blockIdx.x;          // k*256+n
  int lane = threadIdx.x;        // 64
  const float* p = scores + (long)row * VOC;
  float best = 3.4e38f; int bi = 0;
  for (int i = 0; i < 16; ++i) {
    int v = i * 64 + lane;
    float x = p[v];
    if (x < best) { best = x; bi = v; }
  }
  for (int off = 32; off; off >>= 1) {
    float ob = __shfl_down(best, off);
    int oi = __shfl_down(bi, off);
    if (ob < best || (ob == best && oi < bi)) { best = ob; bi = oi; }
  }
  if (lane == 0) codes[row] = bi;
}

// ---------------- transpose+convert dw1 [7168][2560] fp32 -> dw1t [2560][7168] bf16 ----
__global__ __launch_bounds__(256) void k_dw1t(const float* __restrict__ dw1,
                                              ushort* __restrict__ dw1t) {
  __shared__ __align__(16) ushort T[64 * 72];   // [m][k] tile, pitch 72
  int t = threadIdx.x;
  int k0 = blockIdx.x * 64, m0 = blockIdx.y * 64;
  int kk = t >> 2, mj = (t & 3) * 16;
  const float* src = dw1 + (long)(k0 + kk) * 2560 + m0 + mj;
  float x[16];
  *(float4*)&x[0]  = *(const float4*)(src);
  *(float4*)&x[4]  = *(const float4*)(src + 4);
  *(float4*)&x[8]  = *(const float4*)(src + 8);
  *(float4*)&x[12] = *(const float4*)(src + 12);
  #pragma unroll
  for (int l = 0; l < 16; ++l)
    T[(mj + l) * 72 + kk] = f2bf(x[l]);
  __syncthreads();
  int mo = t >> 2, kc = (t & 3) * 16;
  uint4 u0 = *(const uint4*)&T[mo * 72 + kc];
  uint4 u1 = *(const uint4*)&T[mo * 72 + kc + 8];
  ushort* dst = dw1t + (long)(m0 + mo) * C3 + k0 + kc;
  *(uint4*)dst = u0;
  *(uint4*)(dst + 8) = u1;
}

// ---------------- gather q as bf16: qbf[n][k*512+d] = bf16(cb[k, code, d]) ----------
__global__ void k_gather_qbf(const float* __restrict__ cb, const int* __restrict__ codes,
                             ushort* __restrict__ qbf) {
  int idx = blockIdx.x * 256 + threadIdx.x;      // pair index
  const int total = NN * C3 / 2;                 // 917504
  if (idx >= total) return;
  int n = idx / 3584, rr = idx - n * 3584;       // rr = k*256 + dp
  int k = rr >> 8, dp = rr & 255;
  int code = codes[k * NN + n];
  const float* s = cb + ((long)(k * VOC + code)) * DIMV + dp * 2;
  uint lo = f2bf(s[0]), hi = f2bf(s[1]);
  ((uint*)qbf)[idx] = lo | (hi << 16);
}

// ---------------- decoder convT GEMM via MFMA bf16 ----------------
// No-LDS direct bf16 fragment loads, zero barriers in the K-loop. 4 waves per
// block each own a disjoint K-quarter (1792) of the same 64x64 output tile;
// one-shot LDS tree-reduce at the end.
__global__ __launch_bounds__(256) void gemm_a1_mfma(const ushort* __restrict__ dw1t,
    const ushort* __restrict__ qbf, float* __restrict__ a1raw) {
  // red[wave][chunk=i*4+j][lane] as float4 -> 4*16*64*4 floats = 64 KB
  __shared__ __align__(16) float red[4 * 4096];
  const int tid = threadIdx.x;
  const int w = tid >> 6, lane = tid & 63;
  const int l15 = lane & 15, quad = lane >> 4;
  const int m0 = blockIdx.x * 64, n0 = blockIdx.y * 64;
  const int kbase = w * 1792;                 // disjoint K-quarter per wave
  f32x4 acc[4][4] = {};
  const ushort* aB = dw1t + (long)(m0 + l15) * C3 + kbase + quad * 8;
  const ushort* bB = qbf  + (long)(n0 + l15) * C3 + kbase + quad * 8;
  #pragma unroll 2
  for (int k0 = 0; k0 < 1792; k0 += 32) {
    short8 ah[4], bh[4];
    #pragma unroll
    for (int f = 0; f < 4; ++f) {
      ah[f] = *(const short8*)(aB + (long)f * 16 * C3 + k0);
      bh[f] = *(const short8*)(bB + (long)f * 16 * C3 + k0);
    }
    #pragma unroll
    for (int i = 0; i < 4; ++i)
      #pragma unroll
      for (int j = 0; j < 4; ++j)
        acc[i][j] = __builtin_amdgcn_mfma_f32_16x16x32_bf16(ah[i], bh[j], acc[i][j], 0, 0, 0);
  }
  // stash partials: region w, chunk (i*4+j), lane-contiguous float4 (conflict-free)
  #pragma unroll
  for (int i = 0; i < 4; ++i)
    #pragma unroll
    for (int j = 0; j < 4; ++j)
      *(float4*)&red[w * 4096 + (i * 4 + j) * 256 + lane * 4] = *(float4*)&acc[i][j];
  __syncthreads();
  // wave w reduces the 4 K-partials for row-block i=w and scatters to a1raw
  #pragma unroll
  for (int j = 0; j < 4; ++j) {
    float4 s = *(const float4*)&red[(w * 4 + j) * 256 + lane * 4];
    #pragma unroll
    for (int r = 1; r < 4; ++r) {
      float4 tt = *(const float4*)&red[r * 4096 + (w * 4 + j) * 256 + lane * 4];
      s.x += tt.x; s.y += tt.y; s.z += tt.z; s.w += tt.w;
    }
    const int n = n0 + j * 16 + l15;
    const int mb = m0 + w * 16 + quad * 4;
    float v[4] = {s.x, s.y, s.z, s.w};
    #pragma unroll
    for (int reg = 0; reg < 4; ++reg) {
      int m = mb + reg;
      int c = m / 5, jj = m - c * 5;
      a1raw[((long)(n * 5 + jj)) * C2 + c] = v[reg];
    }
  }
}

// ---------------- k_x2: build conv2 im2col X (bf16 hi/lo) from a1raw/ab1 ----------
__global__ void k_x2(const float* __restrict__ a1raw, const float* __restrict__ ab1g,
                     const float* __restrict__ db1, ushort* __restrict__ Xh,
                     ushort* __restrict__ Xl) {
  int idx = blockIdx.x * 256 + threadIdx.x;
  const int total = 2304 * 2560;
  for (; idx < total; idx += gridDim.x * 256) {
    int nu = idx / 2560, ck = idx - nu * 2560;
    int n = nu / 9, u = nu - n * 9;
    int c = ck / 5, jj = ck - c * 5;
    int w = u + jj;
    int s = n & 127;
    int tc = HOP * s - 6 + w;
    float v;
    if (tc < 0 || tc > TOUT - 1) v = 0.f;
    else if (w >= 4 && w <= 8)
      v = fmaxf(db1[c] + a1raw[((long)(n * 5 + (w - 4))) * C2 + c], 0.f);
    else v = ab1g[c];
    uint bi = __float_as_uint(v);
    Xh[idx] = (ushort)(bi >> 16);
    float rr = v - __uint_as_float(bi & 0xffff0000u);
    Xl[idx] = (ushort)(__float_as_uint(rr) >> 16);
  }
}

// ---------------- decoder conv2 as GEMM: a2act = relu(db2 + dw2 . X^T) ----------
// 4-wave blocks, disjoint K-quarter (640) per wave, barrier-free K-loop with
// direct loads (A fp32 split OTF), LDS reduce epilogue.
__global__ __launch_bounds__(256) void gemm_dec2(const float* __restrict__ dw2,
    const ushort* __restrict__ Xh, const ushort* __restrict__ Xl,
    const float* __restrict__ db2, float* __restrict__ a2act) {
  __shared__ __align__(16) float red[4 * 4096];   // 64 KB
  const int tid = threadIdx.x;
  const int w = tid >> 6, lane = tid & 63;
  const int l15 = lane & 15, quad = lane >> 4;
  const int m0 = blockIdx.x * 64, n0 = blockIdx.y * 64;
  const int kbase = w * 640;                  // disjoint K-quarter per wave
  f32x4 acc[4][4] = {};
  const float*  aB = dw2 + (long)(m0 + l15) * 2560 + kbase + quad * 8;
  const ushort* bhB = Xh + (long)(n0 + l15) * 2560 + kbase + quad * 8;
  const ushort* blB = Xl + (long)(n0 + l15) * 2560 + kbase + quad * 8;
  for (int k0 = 0; k0 < 640; k0 += 32) {
    short8 ah[4], al[4], bh[4], bl[4];
    #pragma unroll
    for (int f = 0; f < 4; ++f) {
      const float* ap = aB + (long)f * 16 * 2560 + k0;
      float4 x0 = *(const float4*)ap;
      float4 x1 = *(const float4*)(ap + 4);
      split8(x0, x1, ah[f], al[f]);
      bh[f] = *(const short8*)(bhB + (long)f * 16 * 2560 + k0);
      bl[f] = *(const short8*)(blB + (long)f * 16 * 2560 + k0);
    }
    #pragma unroll
    for (int i = 0; i < 4; ++i)
      #pragma unroll
      for (int j = 0; j < 4; ++j) {
        acc[i][j] = __builtin_amdgcn_mfma_f32_16x16x32_bf16(ah[i], bh[j], acc[i][j], 0, 0, 0);
        acc[i][j] = __builtin_amdgcn_mfma_f32_16x16x32_bf16(ah[i], bl[j], acc[i][j], 0, 0, 0);
        acc[i][j] = __builtin_amdgcn_mfma_f32_16x16x32_bf16(al[i], bh[j], acc[i][j], 0, 0, 0);
      }
  }
  // stash partials: region w, chunk (i*4+j), lane-contiguous float4 (2-way = free)
  #pragma unroll
  for (int i = 0; i < 4; ++i)
    #pragma unroll
    for (int j = 0; j < 4; ++j)
      *(float4*)&red[w * 4096 + (i * 4 + j) * 256 + lane * 4] = *(float4*)&acc[i][j];
  __syncthreads();
  // wave w reduces the 4 K-partials for row-block i=w, applies bias+relu, stores
  const int mb = m0 + w * 16 + quad * 4;
  float4 bias = *(const float4*)(db2 + mb);
  #pragma unroll
  for (int j = 0; j < 4; ++j) {
    float4 s = *(const float4*)&red[(w * 4 + j) * 256 + lane * 4];
    #pragma unroll
    for (int r = 1; r < 4; ++r) {
      float4 tt = *(const float4*)&red[r * 4096 + (w * 4 + j) * 256 + lane * 4];
      s.x += tt.x; s.y += tt.y; s.z += tt.z; s.w += tt.w;
    }
    const int nu = n0 + j * 16 + l15;
    float4 out;
    out.x = fmaxf(s.x + bias.x, 0.f);
    out.y = fmaxf(s.y + bias.y, 0.f);
    out.z = fmaxf(s.z + bias.z, 0.f);
    out.w = fmaxf(s.w + bias.w, 0.f);
    *(float4*)(a2act + (long)nu * C1 + mb) = out;
  }
}

// ---------------- fill output with the constant tanh value ----------------
__global__ void k_fill(float* __restrict__ outp, const float* __restrict__ cconst) {
  float v = cconst[0];
  int idx = blockIdx.x * 256 + threadIdx.x;
  const int total = NBATCH * TOUT;
  for (; idx < total; idx += gridDim.x * 256) outp[idx] = v;
}

// ---------------- decoder conv3+tanh on 15 active cols per (b,s) ----------------
__global__ __launch_bounds__(256) void k_dec3(const float* __restrict__ a2act,
    const float* __restrict__ ab2g, const float* __restrict__ dw3,
    const float* __restrict__ db3, float* __restrict__ outp) {
  __shared__ float sa2[9 * C1];
  __shared__ float sb[C1];
  int n = blockIdx.x;
  int s = n & 127, b = n >> 7;
  int t = threadIdx.x;
  for (int i = t; i < 9 * C1; i += 256) sa2[i] = a2act[(long)n * 9 * C1 + i];
  sb[t] = ab2g[t];
  __syncthreads();
  int wv = t >> 6, lane = t & 63;
  float b3 = db3[0];
  for (int w15 = wv; w15 < 15; w15 += 4) {
    int tc = HOP * s - 7 + w15;
    if (tc < 0 || tc > TOUT - 1) continue;
    float part = 0.f;
    for (int cc = lane; cc < C1; cc += 64) {
      #pragma unroll
      for (int j = 0; j < 7; ++j) {
        int wcol = tc + j - 3;
        float x;
        if (wcol < 0 || wcol > TOUT - 1) x = 0.f;
        else {
          int du = wcol - (HOP * s - 4);
          x = (du >= 0 && du <= 8) ? sa2[du * C1 + cc] : sb[cc];
        }
        part = fmaf(dw3[cc*7+j], x, part);
      }
    }
    for (int off = 32; off; off >>= 1) part += __shfl_down(part, off);
    if (lane == 0) outp[(long)b * TOUT + tc] = tanhf(part + b3);
  }
}

extern "C" void kernel_launch(void* const* d_in, const int* in_sizes, int n_in,
                              void* d_out, int out_size, void* d_ws, size_t ws_size,
                              hipStream_t stream) {
  const float* audio = (const float*)d_in[0];
  const float* cb    = (const float*)d_in[1];
  const float* ew1   = (const float*)d_in[2];
  const float* eb1   = (const float*)d_in[3];
  const float* ew2   = (const float*)d_in[4];
  const float* eb2   = (const float*)d_in[5];
  const float* ew3   = (const float*)d_in[6];
  const float* eb3   = (const float*)d_in[7];
  const float* dw1   = (const float*)d_in[8];
  const float* db1   = (const float*)d_in[9];
  const float* dw2   = (const float*)d_in[10];
  const float* db2   = (const float*)d_in[11];
  const float* dw3   = (const float*)d_in[12];
  const float* db3   = (const float*)d_in[13];
  float* outp = (float*)d_out;
  float* ws = (float*)d_ws;

  float*  cbn    = ws + OFF_CBN;
  float*  ab1    = ws + OFF_AB1;
  float*  ab2    = ws + OFF_AB2;
  float*  cconst = ws + OFF_CCONST;
  float*  h2c    = ws + OFF_H2C;
  ushort* h2xh   = (ushort*)(ws + OFF_H2XH);
  ushort* h2xl   = (ushort*)(ws + OFF_H2XL);
  ushort* h3h    = (ushort*)(ws + OFF_H3H);
  ushort* h3l    = (ushort*)(ws + OFF_H3L);
  float*  scores = ws + OFF_SCORES;
  ushort* X1h    = (ushort*)(ws + OFF_X1H);
  ushort* X1l    = (ushort*)(ws + OFF_X1L);
  ushort* dw1t   = (ushort*)(ws + OFF_DW1T);
  ushort* Xh     = (ushort*)(ws + OFF_XH);
  ushort* Xl     = (ushort*)(ws + OFF_XL);
  int*    codes  = (int*)(ws + OFF_CODES);
  ushort* qbf    = (ushort*)(ws + OFF_QBF);
  float*  a1raw  = ws + OFF_A1RAW;
  float*  a2act  = ws + OFF_A2ACT;

  k_cbn<<<3584, 256, 0, stream>>>(cb, cbn);
  k_prep_ab2<<<C1, 256, 0, stream>>>(db1, dw2, db2, ab1, ab2);
  k_prep_c<<<1, 256, 0, stream>>>(dw3, db3, ab2, cconst);
  k_enc1<<<NN, 256, 0, stream>>>(audio, ew1, eb1, X1h, X1l);
  gemm_enc2<<<dim3(16, 4), 64, 0, stream>>>(ew2, X1h, X1l, eb2, h2c);
  k_h2x<<<384, 256, 0, stream>>>(h2c, h2xh, h2xl);
  gemm_h3<<<dim3(112, 4), 256, 0, stream>>>(ew3, h2xh, h2xl, eb3, h3h, h3l);
  // gemm_scores writes over X1h/X1l (dead after gemm_enc2) — stream-ordered
  gemm_scores<<<dim3(16, 4, 14), 256, 0, stream>>>(cb, h3h, h3l, cbn, scores);
  k_argmin<<<NCBK * NN, 64, 0, stream>>>(scores, codes);
  // dw1t overlaps h3h/h3l/scores memory: must launch AFTER k_argmin (stream-ordered)
  k_dw1t<<<dim3(112, 40), 256, 0, stream>>>(dw1, dw1t);
  k_gather_qbf<<<3584, 256, 0, stream>>>(cb, codes, qbf);
  gemm_a1_mfma<<<dim3(40, 4), 256, 0, stream>>>(dw1t, qbf, a1raw);
  // Xh/Xl overlap dw1t memory: must launch AFTER gemm_a1_mfma (stream-ordered)
  k_x2<<<4096, 256, 0, stream>>>(a1raw, ab1, db1, Xh, Xl);
  gemm_dec2<<<dim3(4, 36), 256, 0, stream>>>(dw2, Xh, Xl, db2, a2act);
  k_fill<<<256, 256, 0, stream>>>(outp, cconst);
  k_dec3<<<NN, 256, 0, stream>>>(a2act, ab2, dw3, db3, outp);
}

// Round 4
// 441.852 us; speedup vs baseline: 1.2530x; 1.0523x over previous
//
#include <hip/hip_runtime.h>
#include <hip/hip_bf16.h>
#include <math.h>

#define T_IN 98304
#define SS 128
#define NBATCH 2
#define NN 256          // NBATCH*SS
#define C1 256
#define C2 512
#define C3 7168
#define NCBK 14
#define DIMV 512
#define VOC 1024
#define TOUT 97537
#define HOP 768

// ws layout (float offsets)
#define OFF_CBN    0L          // 14336
#define OFF_AB1    14336L      // 512
#define OFF_AB2    14848L      // 256
#define OFF_CCONST 15104L      // 16
#define OFF_H2C    15120L      // 131072   (n*512+ic), n=b*128+s
#define OFF_H2XH   146192L     // 196608 fl (ushort [256][1536] bf16-hi)
#define OFF_H2XL   342800L     // 196608 fl (bf16-lo)
#define OFF_H3H    539408L     // 917504 fl (ushort [256][7168] bf16-hi)
#define OFF_H3L    1456912L    // 917504 fl
#define OFF_SCORES 2374416L    // 3670016  ((k*256+n)*1024 + v)
// X1h/X1l (bf16 [256][1280] = 163840 fl each) OVERLAP scores region: X1 is dead
// before gemm_scores writes scores (same stream serializes).
#define OFF_X1H    2374416L    // ends 2538256
#define OFF_X1L    2538256L    // ends 2702096
// dw1t (bf16 [2560][7168] = 9175040 fl) OVERLAPS h3h/h3l/scores: all dead
// before k_dw1t runs (launched after k_argmin; same stream serializes).
#define OFF_DW1T   539408L     // ends 9714448
// Xh/Xl (bf16 [2304][2560] each = 2949120 fl each) OVERLAP dw1t: dw1t is dead
// after gemm_a1_mfma; k_x2 launches after it (same stream serializes).
#define OFF_XH     539408L     // ends 3488528
#define OFF_XL     3488528L    // ends 6437648
#define OFF_CODES  9714448L    // 3584 ints
#define OFF_QBF    9718032L    // 917504 fl (bf16 [256][7168])
#define OFF_A1RAW  10635536L   // 655360   ((n*5+j)*512 + c)  pre-bias/relu
#define OFF_A2ACT  11290896L   // 589824   ((n*9+u)*256 + o)  post-relu
// total 11880720 floats = 47.5 MB

typedef __attribute__((ext_vector_type(8))) short short8;
typedef __attribute__((ext_vector_type(4))) float f32x4;

static __device__ inline ushort f2bf(float x) {
  __hip_bfloat16 h = __float2bfloat16(x);
  return *reinterpret_cast<ushort*>(&h);
}

// exact 2-term split: x = hi + lo + O(2^-16 |x|); truncation split, residual exact
static __device__ inline void split8(const float4 x0, const float4 x1,
                                     short8& h, short8& l) {
  float xs[8] = {x0.x, x0.y, x0.z, x0.w, x1.x, x1.y, x1.z, x1.w};
  #pragma unroll
  for (int e = 0; e < 8; ++e) {
    uint b = __float_as_uint(xs[e]);
    h[e] = (short)(b >> 16);
    float r = xs[e] - __uint_as_float(b & 0xffff0000u);
    l[e] = (short)(__float_as_uint(r) >> 16);
  }
}

// ---------------- prep: codebook norms ----------------
__global__ void k_cbn(const float* __restrict__ cb, float* __restrict__ cbn) {
  int row = blockIdx.x * 4 + (threadIdx.x >> 6);
  int lane = threadIdx.x & 63;
  const float* p = cb + (long)row * DIMV;
  float s = 0.f;
  for (int d = lane; d < DIMV; d += 64) { float x = p[d]; s += x * x; }
  for (int off = 32; off; off >>= 1) s += __shfl_down(s, off);
  if (lane == 0) cbn[row] = s;
}

// ---------------- prep A: ab1 = relu(db1); ab2[o] = relu(db2[o]+sum_c W(o,c)*ab1[c])
__global__ __launch_bounds__(256) void k_prep_ab2(const float* __restrict__ db1,
    const float* __restrict__ dw2, const float* __restrict__ db2,
    float* __restrict__ ab1, float* __restrict__ ab2) {
  __shared__ float red[256];
  int o = blockIdx.x, t = threadIdx.x;
  if (o == 0) { ab1[t] = fmaxf(db1[t], 0.f); ab1[t + 256] = fmaxf(db1[t + 256], 0.f); }
  const float* wp = dw2 + (long)o * C2 * 5;
  float acc = 0.f;
  #pragma unroll
  for (int h = 0; h < 2; ++h) {
    int c = t + h * 256;
    const float* p = wp + c * 5;
    float wsum = p[0] + p[1] + p[2] + p[3] + p[4];
    acc = fmaf(wsum, fmaxf(db1[c], 0.f), acc);
  }
  red[t] = acc;
  __syncthreads();
  for (int off = 128; off; off >>= 1) {
    if (t < off) red[t] += red[t + off];
    __syncthreads();
  }
  if (t == 0) ab2[o] = fmaxf(red[0] + db2[o], 0.f);
}

// ---------------- prep B: cconst = tanh(db3 + sum_o (sum_j dw3[o][j]) * ab2[o]) ----
__global__ __launch_bounds__(256) void k_prep_c(const float* __restrict__ dw3,
    const float* __restrict__ db3, const float* __restrict__ ab2,
    float* __restrict__ cconst) {
  __shared__ float red[256];
  int t = threadIdx.x;
  float wsum3 = 0.f;
  #pragma unroll
  for (int j = 0; j < 7; ++j) wsum3 += dw3[t*7+j];
  red[t] = wsum3 * ab2[t];
  __syncthreads();
  for (int off = 128; off; off >>= 1) {
    if (t < off) red[t] += red[t + off];
    __syncthreads();
  }
  if (t == 0) cconst[0] = tanhf(red[0] + db3[0]);
}

// ---------------- encoder conv1 (k7,p3) at the 5 cols conv2 needs, as im2col ------
// X1[n][ic*5+jj] = h1[b][ic][768s+jj-2]  (0 if tcol<0: conv2 zero pad)
__global__ __launch_bounds__(256) void k_enc1(const float* __restrict__ audio,
    const float* __restrict__ ew1, const float* __restrict__ eb1,
    ushort* __restrict__ X1h, ushort* __restrict__ X1l) {
  int n = blockIdx.x, ic = threadIdx.x;
  int b = n >> 7, s = n & 127;
  const float* ap = audio + (long)b * T_IN;
  int base = HOP * s - 5;           // audio idx for window pos 0
  float a[11];
  #pragma unroll
  for (int w = 0; w < 11; ++w) {
    int ai = base + w;
    a[w] = (ai >= 0 && ai < T_IN) ? ap[ai] : 0.f;
  }
  float w1[7];
  #pragma unroll
  for (int j = 0; j < 7; ++j) w1[j] = ew1[ic*7+j];
  float b1 = eb1[ic];
  long off = (long)n * 1280 + ic * 5;
  #pragma unroll
  for (int jj = 0; jj < 5; ++jj) {
    int tcol = HOP * s + jj - 2;
    float v = 0.f;
    if (tcol >= 0) {
      float acc = b1;
      #pragma unroll
      for (int j = 0; j < 7; ++j) acc = fmaf(w1[j], a[jj + j], acc);
      v = fmaxf(acc, 0.f);
    }
    uint bi = __float_as_uint(v);
    X1h[off + jj] = (ushort)(bi >> 16);
    float r = v - __uint_as_float(bi & 0xffff0000u);
    X1l[off + jj] = (ushort)(__float_as_uint(r) >> 16);
  }
}

// ---------------- encoder conv2 as GEMM: h2c[n][oc] = relu(eb2 + ew2 . X1^T) ------
// 4-wave blocks, disjoint K-quarter (320) per wave, barrier-free K-loop,
// LDS reduce epilogue (wave w reduces chunks 2w, 2w+1).
__global__ __launch_bounds__(256) void gemm_enc2(const float* __restrict__ ew2,
    const ushort* __restrict__ X1h, const ushort* __restrict__ X1l,
    const float* __restrict__ eb2, float* __restrict__ h2c) {
  __shared__ __align__(16) float red[4 * 2048];   // 32 KB: [wave][chunk 0..7][lane][4]
  const int tid = threadIdx.x;
  const int w = tid >> 6, lane = tid & 63;
  const int l15 = lane & 15, quad = lane >> 4;
  const int m0 = blockIdx.x * 32, n0 = blockIdx.y * 64;
  const int kbase = w * 320;                  // disjoint K-quarter per wave
  f32x4 acc[2][4] = {};
  const float*  aB = ew2 + (long)(m0 + l15) * 1280 + kbase + quad * 8;
  const ushort* bhB = X1h + (long)(n0 + l15) * 1280 + kbase + quad * 8;
  const ushort* blB = X1l + (long)(n0 + l15) * 1280 + kbase + quad * 8;
  for (int k0 = 0; k0 < 320; k0 += 32) {
    short8 ah[2], al[2], bh[4], bl[4];
    #pragma unroll
    for (int f = 0; f < 2; ++f) {
      const float* ap = aB + (long)f * 16 * 1280 + k0;
      float4 x0 = *(const float4*)ap;
      float4 x1 = *(const float4*)(ap + 4);
      split8(x0, x1, ah[f], al[f]);
    }
    #pragma unroll
    for (int f = 0; f < 4; ++f) {
      bh[f] = *(const short8*)(bhB + (long)f * 16 * 1280 + k0);
      bl[f] = *(const short8*)(blB + (long)f * 16 * 1280 + k0);
    }
    #pragma unroll
    for (int i = 0; i < 2; ++i)
      #pragma unroll
      for (int j = 0; j < 4; ++j) {
        acc[i][j] = __builtin_amdgcn_mfma_f32_16x16x32_bf16(ah[i], bh[j], acc[i][j], 0, 0, 0);
        acc[i][j] = __builtin_amdgcn_mfma_f32_16x16x32_bf16(ah[i], bl[j], acc[i][j], 0, 0, 0);
        acc[i][j] = __builtin_amdgcn_mfma_f32_16x16x32_bf16(al[i], bh[j], acc[i][j], 0, 0, 0);
      }
  }
  #pragma unroll
  for (int i = 0; i < 2; ++i)
    #pragma unroll
    for (int j = 0; j < 4; ++j)
      *(float4*)&red[w * 2048 + (i * 4 + j) * 256 + lane * 4] = *(float4*)&acc[i][j];
  __syncthreads();
  #pragma unroll
  for (int q = 0; q < 2; ++q) {
    const int c = 2 * w + q;
    const int i = c >> 2, j = c & 3;
    float4 s = make_float4(0.f, 0.f, 0.f, 0.f);
    #pragma unroll
    for (int g = 0; g < 4; ++g) {
      float4 t4 = *(const float4*)&red[g * 2048 + c * 256 + lane * 4];
      s.x += t4.x; s.y += t4.y; s.z += t4.z; s.w += t4.w;
    }
    const int obase = m0 + i * 16 + quad * 4;
    float4 bias = *(const float4*)(eb2 + obase);
    const int n = n0 + j * 16 + l15;
    float4 out;
    out.x = fmaxf(s.x + bias.x, 0.f);
    out.y = fmaxf(s.y + bias.y, 0.f);
    out.z = fmaxf(s.z + bias.z, 0.f);
    out.w = fmaxf(s.w + bias.w, 0.f);
    *(float4*)(h2c + (long)n * C2 + obase) = out;
  }
}

// ---------------- im2col for conv3 (k3,p1), written as bf16 hi/lo split ----------
__global__ void k_h2x(const float* __restrict__ h2c, ushort* __restrict__ h2xh,
                      ushort* __restrict__ h2xl) {
  int idx = blockIdx.x * 256 + threadIdx.x;
  const int total = NN * 1536;
  for (; idx < total; idx += gridDim.x * 256) {
    int n = idx / 1536, r = idx - n * 1536;
    int ic = r / 3, j = r - ic * 3;
    int s2 = (n & 127) + j - 1;
    int b = n >> 7;
    float v = (s2 >= 0 && s2 < SS) ? h2c[(long)(b*SS + s2)*C2 + ic] : 0.f;
    uint bi = __float_as_uint(v);
    h2xh[idx] = (ushort)(bi >> 16);
    float rr = v - __uint_as_float(bi & 0xffff0000u);
    h2xl[idx] = (ushort)(__float_as_uint(rr) >> 16);
  }
}

// ---------------- S1: h3 = ew3 . h2x^T + eb3 ----------------
// 4-wave blocks, disjoint K-quarter (384) per wave, barrier-free K-loop,
// LDS reduce epilogue.
__global__ __launch_bounds__(256) void gemm_h3(const float* __restrict__ A,
    const ushort* __restrict__ Bh, const ushort* __restrict__ Bl,
    const float* __restrict__ eb3, ushort* __restrict__ h3h, ushort* __restrict__ h3l) {
  __shared__ __align__(16) float red[4 * 4096];   // 64 KB
  const int tid = threadIdx.x;
  const int w = tid >> 6, lane = tid & 63;
  const int l15 = lane & 15, quad = lane >> 4;
  const int m0 = blockIdx.x * 64, n0 = blockIdx.y * 64;
  const int kbase = w * 384;                  // disjoint K-quarter per wave
  f32x4 acc[4][4] = {};
  const float*  aB = A  + (long)(m0 + l15) * 1536 + kbase + quad * 8;
  const ushort* bhB = Bh + (long)(n0 + l15) * 1536 + kbase + quad * 8;
  const ushort* blB = Bl + (long)(n0 + l15) * 1536 + kbase + quad * 8;
  for (int k0 = 0; k0 < 384; k0 += 32) {
    short8 ah[4], al[4], bh[4], bl[4];
    #pragma unroll
    for (int f = 0; f < 4; ++f) {
      const float* ap = aB + (long)f * 16 * 1536 + k0;
      float4 x0 = *(const float4*)ap;
      float4 x1 = *(const float4*)(ap + 4);
      split8(x0, x1, ah[f], al[f]);
      bh[f] = *(const short8*)(bhB + (long)f * 16 * 1536 + k0);
      bl[f] = *(const short8*)(blB + (long)f * 16 * 1536 + k0);
    }
    #pragma unroll
    for (int i = 0; i < 4; ++i)
      #pragma unroll
      for (int j = 0; j < 4; ++j) {
        acc[i][j] = __builtin_amdgcn_mfma_f32_16x16x32_bf16(ah[i], bh[j], acc[i][j], 0, 0, 0);
        acc[i][j] = __builtin_amdgcn_mfma_f32_16x16x32_bf16(ah[i], bl[j], acc[i][j], 0, 0, 0);
        acc[i][j] = __builtin_amdgcn_mfma_f32_16x16x32_bf16(al[i], bh[j], acc[i][j], 0, 0, 0);
      }
  }
  // stash partials: region w, chunk (i*4+j), lane-contiguous float4 (2-way = free)
  #pragma unroll
  for (int i = 0; i < 4; ++i)
    #pragma unroll
    for (int j = 0; j < 4; ++j)
      *(float4*)&red[w * 4096 + (i * 4 + j) * 256 + lane * 4] = *(float4*)&acc[i][j];
  __syncthreads();
  // wave w reduces the 4 K-partials for row-block i=w, adds bias, packs hi/lo
  const int mbase = m0 + w * 16 + quad * 4;
  float4 bias = *(const float4*)(eb3 + mbase);
  #pragma unroll
  for (int j = 0; j < 4; ++j) {
    float4 s = *(const float4*)&red[(w * 4 + j) * 256 + lane * 4];
    #pragma unroll
    for (int r = 1; r < 4; ++r) {
      float4 tt = *(const float4*)&red[r * 4096 + (w * 4 + j) * 256 + lane * 4];
      s.x += tt.x; s.y += tt.y; s.z += tt.z; s.w += tt.w;
    }
    const int n = n0 + j * 16 + l15;
    float v0 = s.x + bias.x;
    float v1 = s.y + bias.y;
    float v2 = s.z + bias.z;
    float v3 = s.w + bias.w;
    uint b0 = __float_as_uint(v0), b1 = __float_as_uint(v1);
    uint b2 = __float_as_uint(v2), b3 = __float_as_uint(v3);
    uint2 hp;
    hp.x = (b0 >> 16) | (b1 & 0xffff0000u);
    hp.y = (b2 >> 16) | (b3 & 0xffff0000u);
    float r0 = v0 - __uint_as_float(b0 & 0xffff0000u);
    float r1 = v1 - __uint_as_float(b1 & 0xffff0000u);
    float r2 = v2 - __uint_as_float(b2 & 0xffff0000u);
    float r3 = v3 - __uint_as_float(b3 & 0xffff0000u);
    uint2 lp;
    lp.x = (__float_as_uint(r0) >> 16) | (__float_as_uint(r1) & 0xffff0000u);
    lp.y = (__float_as_uint(r2) >> 16) | (__float_as_uint(r3) & 0xffff0000u);
    long off = (long)n * C3 + mbase;
    *(uint2*)(h3h + off) = hp;
    *(uint2*)(h3l + off) = lp;
  }
}

// ---------------- S2: scores = cbn - 2*cb.h3^T ----------------
// 4-wave blocks, disjoint K-quarter (128) per wave, barrier-free K-loop,
// LDS reduce epilogue.
__global__ __launch_bounds__(256) void gemm_scores(const float* __restrict__ cb,
    const ushort* __restrict__ h3h, const ushort* __restrict__ h3l,
    const float* __restrict__ cbn, float* __restrict__ scores) {
  __shared__ __align__(16) float red[4 * 4096];   // 64 KB
  const int tid = threadIdx.x;
  const int w = tid >> 6, lane = tid & 63;
  const int l15 = lane & 15, quad = lane >> 4;
  const int m0 = blockIdx.x * 64, n0 = blockIdx.y * 64, z = blockIdx.z;
  const int kbase = w * 128;                  // disjoint K-quarter per wave
  f32x4 acc[4][4] = {};
  const float*  aB = cb + (long)z * VOC * DIMV + (long)(m0 + l15) * 512 + kbase + quad * 8;
  const ushort* bhB = h3h + (long)(n0 + l15) * C3 + z * 512 + kbase + quad * 8;
  const ushort* blB = h3l + (long)(n0 + l15) * C3 + z * 512 + kbase + quad * 8;
  for (int k0 = 0; k0 < 128; k0 += 32) {
    short8 ah[4], al[4], bh[4], bl[4];
    #pragma unroll
    for (int f = 0; f < 4; ++f) {
      const float* ap = aB + (long)f * 16 * 512 + k0;
      float4 x0 = *(const float4*)ap;
      float4 x1 = *(const float4*)(ap + 4);
      split8(x0, x1, ah[f], al[f]);
      bh[f] = *(const short8*)(bhB + (long)f * 16 * C3 + k0);
      bl[f] = *(const short8*)(blB + (long)f * 16 * C3 + k0);
    }
    #pragma unroll
    for (int i = 0; i < 4; ++i)
      #pragma unroll
      for (int j = 0; j < 4; ++j) {
        acc[i][j] = __builtin_amdgcn_mfma_f32_16x16x32_bf16(ah[i], bh[j], acc[i][j], 0, 0, 0);
        acc[i][j] = __builtin_amdgcn_mfma_f32_16x16x32_bf16(ah[i], bl[j], acc[i][j], 0, 0, 0);
        acc[i][j] = __builtin_amdgcn_mfma_f32_16x16x32_bf16(al[i], bh[j], acc[i][j], 0, 0, 0);
      }
  }
  // stash partials
  #pragma unroll
  for (int i = 0; i < 4; ++i)
    #pragma unroll
    for (int j = 0; j < 4; ++j)
      *(float4*)&red[w * 4096 + (i * 4 + j) * 256 + lane * 4] = *(float4*)&acc[i][j];
  __syncthreads();
  // wave w reduces the 4 K-partials for row-block i=w, applies cbn - 2*acc
  const int vbase = m0 + w * 16 + quad * 4;
  float4 cn = *(const float4*)(cbn + z * VOC + vbase);
  #pragma unroll
  for (int j = 0; j < 4; ++j) {
    float4 s = *(const float4*)&red[(w * 4 + j) * 256 + lane * 4];
    #pragma unroll
    for (int r = 1; r < 4; ++r) {
      float4 tt = *(const float4*)&red[r * 4096 + (w * 4 + j) * 256 + lane * 4];
      s.x += tt.x; s.y += tt.y; s.z += tt.z; s.w += tt.w;
    }
    const int n = n0 + j * 16 + l15;
    float4 out;
    out.x = cn.x - 2.f * s.x;
    out.y = cn.y - 2.f * s.y;
    out.z = cn.z - 2.f * s.z;
    out.w = cn.w - 2.f * s.w;
    *(float4*)(scores + ((long)z * NN + n) * VOC + vbase) = out;
  }
}

// ---------------- argmin over 1024 codes, numpy tie-break (lowest v) ----------------
__global__ void k_argmin(const float* __restrict__ scores, int* __restrict__ codes) {
  int row = blockIdx.x;          // k*256+n
  int lane = threadIdx.x;        // 64
  const float* p = scores + (long)row * VOC;
  float best = 3.4e38f; int bi = 0;
  for (int i = 0; i < 16; ++i) {
    int v = i * 64 + lane;
    float x = p[v];
    if (x < best) { best = x; bi = v; }
  }
  for (int off = 32; off; off >>= 1) {
    float ob = __shfl_down(best, off);
    int oi = __shfl_down(bi, off);
    if (ob < best || (ob == best && oi < bi)) { best = ob; bi = oi; }
  }
  if (lane == 0) codes[row] = bi;
}

// ---------------- transpose+convert dw1 [7168][2560] fp32 -> dw1t [2560][7168] bf16 ----
__global__ __launch_bounds__(256) void k_dw1t(const float* __restrict__ dw1,
                                              ushort* __restrict__ dw1t) {
  __shared__ __align__(16) ushort T[64 * 72];   // [m][k] tile, pitch 72
  int t = threadIdx.x;
  int k0 = blockIdx.x * 64, m0 = blockIdx.y * 64;
  int kk = t >> 2, mj = (t & 3) * 16;
  const float* src = dw1 + (long)(k0 + kk) * 2560 + m0 + mj;
  float x[16];
  *(float4*)&x[0]  = *(const float4*)(src);
  *(float4*)&x[4]  = *(const float4*)(src + 4);
  *(float4*)&x[8]  = *(const float4*)(src + 8);
  *(float4*)&x[12] = *(const float4*)(src + 12);
  #pragma unroll
  for (int l = 0; l < 16; ++l)
    T[(mj + l) * 72 + kk] = f2bf(x[l]);
  __syncthreads();
  int mo = t >> 2, kc = (t & 3) * 16;
  uint4 u0 = *(const uint4*)&T[mo * 72 + kc];
  uint4 u1 = *(const uint4*)&T[mo * 72 + kc + 8];
  ushort* dst = dw1t + (long)(m0 + mo) * C3 + k0 + kc;
  *(uint4*)dst = u0;
  *(uint4*)(dst + 8) = u1;
}

// ---------------- gather q as bf16: qbf[n][k*512+d] = bf16(cb[k, code, d]) ----------
__global__ void k_gather_qbf(const float* __restrict__ cb, const int* __restrict__ codes,
                             ushort* __restrict__ qbf) {
  int idx = blockIdx.x * 256 + threadIdx.x;      // pair index
  const int total = NN * C3 / 2;                 // 917504
  if (idx >= total) return;
  int n = idx / 3584, rr = idx - n * 3584;       // rr = k*256 + dp
  int k = rr >> 8, dp = rr & 255;
  int code = codes[k * NN + n];
  const float* s = cb + ((long)(k * VOC + code)) * DIMV + dp * 2;
  uint lo = f2bf(s[0]), hi = f2bf(s[1]);
  ((uint*)qbf)[idx] = lo | (hi << 16);
}

// ---------------- decoder convT GEMM via MFMA bf16 ----------------
// 16-wave (1024-thread) blocks: each wave owns a disjoint K-1/16 (448, 14 iters)
// of the same 64x64 tile; barrier-free K-loop; staged 4-round LDS reduce (64 KB)
// with register-held running sums. Old 4-wave version: 0.625 waves/SIMD,
// 56-iter chains -> 63 us, MfmaUtil 5.4%.
__global__ __launch_bounds__(1024) void gemm_a1_mfma(const ushort* __restrict__ dw1t,
    const ushort* __restrict__ qbf, float* __restrict__ a1raw) {
  // red[region 0..3][chunk 0..15][lane][4] = 64 KB
  __shared__ __align__(16) float red[4 * 4096];
  const int tid = threadIdx.x;
  const int w = tid >> 6, lane = tid & 63;     // w in 0..15
  const int l15 = lane & 15, quad = lane >> 4;
  const int m0 = blockIdx.x * 64, n0 = blockIdx.y * 64;
  const int kbase = w * 448;                   // disjoint K-1/16 per wave
  f32x4 acc[4][4] = {};
  const ushort* aB = dw1t + (long)(m0 + l15) * C3 + kbase + quad * 8;
  const ushort* bB = qbf  + (long)(n0 + l15) * C3 + kbase + quad * 8;
  #pragma unroll 2
  for (int k0 = 0; k0 < 448; k0 += 32) {
    short8 ah[4], bh[4];
    #pragma unroll
    for (int f = 0; f < 4; ++f) {
      ah[f] = *(const short8*)(aB + (long)f * 16 * C3 + k0);
      bh[f] = *(const short8*)(bB + (long)f * 16 * C3 + k0);
    }
    #pragma unroll
    for (int i = 0; i < 4; ++i)
      #pragma unroll
      for (int j = 0; j < 4; ++j)
        acc[i][j] = __builtin_amdgcn_mfma_f32_16x16x32_bf16(ah[i], bh[j], acc[i][j], 0, 0, 0);
  }
  // staged 4-round cross-wave reduce: round r, waves 4r..4r+3 stash all 16
  // chunks; every wave accumulates its owned chunk (c = w) in registers.
  float4 rsum = make_float4(0.f, 0.f, 0.f, 0.f);
  #pragma unroll
  for (int r = 0; r < 4; ++r) {
    if ((w >> 2) == r) {
      #pragma unroll
      for (int i = 0; i < 4; ++i)
        #pragma unroll
        for (int j = 0; j < 4; ++j)
          *(float4*)&red[(w & 3) * 4096 + (i * 4 + j) * 256 + lane * 4] = *(float4*)&acc[i][j];
    }
    __syncthreads();
    #pragma unroll
    for (int g = 0; g < 4; ++g) {
      float4 t4 = *(const float4*)&red[g * 4096 + w * 256 + lane * 4];
      rsum.x += t4.x; rsum.y += t4.y; rsum.z += t4.z; rsum.w += t4.w;
    }
    __syncthreads();
  }
  // wave w holds the final sum for chunk (i = w>>2, j = w&3); scatter to a1raw
  const int ci = w >> 2, cj = w & 3;
  const int n = n0 + cj * 16 + l15;
  const int mb = m0 + ci * 16 + quad * 4;
  float v[4] = {rsum.x, rsum.y, rsum.z, rsum.w};
  #pragma unroll
  for (int reg = 0; reg < 4; ++reg) {
    int m = mb + reg;
    int c = m / 5, jj = m - c * 5;
    a1raw[((long)(n * 5 + jj)) * C2 + c] = v[reg];
  }
}

// ---------------- k_x2: build conv2 im2col X (bf16 hi/lo) from a1raw/ab1 ----------
__global__ void k_x2(const float* __restrict__ a1raw, const float* __restrict__ ab1g,
                     const float* __restrict__ db1, ushort* __restrict__ Xh,
                     ushort* __restrict__ Xl) {
  int idx = blockIdx.x * 256 + threadIdx.x;
  const int total = 2304 * 2560;
  for (; idx < total; idx += gridDim.x * 256) {
    int nu = idx / 2560, ck = idx - nu * 2560;
    int n = nu / 9, u = nu - n * 9;
    int c = ck / 5, jj = ck - c * 5;
    int w = u + jj;
    int s = n & 127;
    int tc = HOP * s - 6 + w;
    float v;
    if (tc < 0 || tc > TOUT - 1) v = 0.f;
    else if (w >= 4 && w <= 8)
      v = fmaxf(db1[c] + a1raw[((long)(n * 5 + (w - 4))) * C2 + c], 0.f);
    else v = ab1g[c];
    uint bi = __float_as_uint(v);
    Xh[idx] = (ushort)(bi >> 16);
    float rr = v - __uint_as_float(bi & 0xffff0000u);
    Xl[idx] = (ushort)(__float_as_uint(rr) >> 16);
  }
}

// ---------------- decoder conv2 as GEMM: a2act = relu(db2 + dw2 . X^T) ----------
// 4-wave blocks, disjoint K-quarter (640) per wave, barrier-free K-loop with
// direct loads (A fp32 split OTF), LDS reduce epilogue.
__global__ __launch_bounds__(256) void gemm_dec2(const float* __restrict__ dw2,
    const ushort* __restrict__ Xh, const ushort* __restrict__ Xl,
    const float* __restrict__ db2, float* __restrict__ a2act) {
  __shared__ __align__(16) float red[4 * 4096];   // 64 KB
  const int tid = threadIdx.x;
  const int w = tid >> 6, lane = tid & 63;
  const int l15 = lane & 15, quad = lane >> 4;
  const int m0 = blockIdx.x * 64, n0 = blockIdx.y * 64;
  const int kbase = w * 640;                  // disjoint K-quarter per wave
  f32x4 acc[4][4] = {};
  const float*  aB = dw2 + (long)(m0 + l15) * 2560 + kbase + quad * 8;
  const ushort* bhB = Xh + (long)(n0 + l15) * 2560 + kbase + quad * 8;
  const ushort* blB = Xl + (long)(n0 + l15) * 2560 + kbase + quad * 8;
  for (int k0 = 0; k0 < 640; k0 += 32) {
    short8 ah[4], al[4], bh[4], bl[4];
    #pragma unroll
    for (int f = 0; f < 4; ++f) {
      const float* ap = aB + (long)f * 16 * 2560 + k0;
      float4 x0 = *(const float4*)ap;
      float4 x1 = *(const float4*)(ap + 4);
      split8(x0, x1, ah[f], al[f]);
      bh[f] = *(const short8*)(bhB + (long)f * 16 * 2560 + k0);
      bl[f] = *(const short8*)(blB + (long)f * 16 * 2560 + k0);
    }
    #pragma unroll
    for (int i = 0; i < 4; ++i)
      #pragma unroll
      for (int j = 0; j < 4; ++j) {
        acc[i][j] = __builtin_amdgcn_mfma_f32_16x16x32_bf16(ah[i], bh[j], acc[i][j], 0, 0, 0);
        acc[i][j] = __builtin_amdgcn_mfma_f32_16x16x32_bf16(ah[i], bl[j], acc[i][j], 0, 0, 0);
        acc[i][j] = __builtin_amdgcn_mfma_f32_16x16x32_bf16(al[i], bh[j], acc[i][j], 0, 0, 0);
      }
  }
  // stash partials: region w, chunk (i*4+j), lane-contiguous float4 (2-way = free)
  #pragma unroll
  for (int i = 0; i < 4; ++i)
    #pragma unroll
    for (int j = 0; j < 4; ++j)
      *(float4*)&red[w * 4096 + (i * 4 + j) * 256 + lane * 4] = *(float4*)&acc[i][j];
  __syncthreads();
  // wave w reduces the 4 K-partials for row-block i=w, applies bias+relu, stores
  const int mb = m0 + w * 16 + quad * 4;
  float4 bias = *(const float4*)(db2 + mb);
  #pragma unroll
  for (int j = 0; j < 4; ++j) {
    float4 s = *(const float4*)&red[(w * 4 + j) * 256 + lane * 4];
    #pragma unroll
    for (int r = 1; r < 4; ++r) {
      float4 tt = *(const float4*)&red[r * 4096 + (w * 4 + j) * 256 + lane * 4];
      s.x += tt.x; s.y += tt.y; s.z += tt.z; s.w += tt.w;
    }
    const int nu = n0 + j * 16 + l15;
    float4 out;
    out.x = fmaxf(s.x + bias.x, 0.f);
    out.y = fmaxf(s.y + bias.y, 0.f);
    out.z = fmaxf(s.z + bias.z, 0.f);
    out.w = fmaxf(s.w + bias.w, 0.f);
    *(float4*)(a2act + (long)nu * C1 + mb) = out;
  }
}

// ---------------- fill output with the constant tanh value ----------------
__global__ void k_fill(float* __restrict__ outp, const float* __restrict__ cconst) {
  float v = cconst[0];
  int idx = blockIdx.x * 256 + threadIdx.x;
  const int total = NBATCH * TOUT;
  for (; idx < total; idx += gridDim.x * 256) outp[idx] = v;
}

// ---------------- decoder conv3+tanh on 15 active cols per (b,s) ----------------
__global__ __launch_bounds__(256) void k_dec3(const float* __restrict__ a2act,
    const float* __restrict__ ab2g, const float* __restrict__ dw3,
    const float* __restrict__ db3, float* __restrict__ outp) {
  __shared__ float sa2[9 * C1];
  __shared__ float sb[C1];
  int n = blockIdx.x;
  int s = n & 127, b = n >> 7;
  int t = threadIdx.x;
  for (int i = t; i < 9 * C1; i += 256) sa2[i] = a2act[(long)n * 9 * C1 + i];
  sb[t] = ab2g[t];
  __syncthreads();
  int wv = t >> 6, lane = t & 63;
  float b3 = db3[0];
  for (int w15 = wv; w15 < 15; w15 += 4) {
    int tc = HOP * s - 7 + w15;
    if (tc < 0 || tc > TOUT - 1) continue;
    float part = 0.f;
    for (int cc = lane; cc < C1; cc += 64) {
      #pragma unroll
      for (int j = 0; j < 7; ++j) {
        int wcol = tc + j - 3;
        float x;
        if (wcol < 0 || wcol > TOUT - 1) x = 0.f;
        else {
          int du = wcol - (HOP * s - 4);
          x = (du >= 0 && du <= 8) ? sa2[du * C1 + cc] : sb[cc];
        }
        part = fmaf(dw3[cc*7+j], x, part);
      }
    }
    for (int off = 32; off; off >>= 1) part += __shfl_down(part, off);
    if (lane == 0) outp[(long)b * TOUT + tc] = tanhf(part + b3);
  }
}

extern "C" void kernel_launch(void* const* d_in, const int* in_sizes, int n_in,
                              void* d_out, int out_size, void* d_ws, size_t ws_size,
                              hipStream_t stream) {
  const float* audio = (const float*)d_in[0];
  const float* cb    = (const float*)d_in[1];
  const float* ew1   = (const float*)d_in[2];
  const float* eb1   = (const float*)d_in[3];
  const float* ew2   = (const float*)d_in[4];
  const float* eb2   = (const float*)d_in[5];
  const float* ew3   = (const float*)d_in[6];
  const float* eb3   = (const float*)d_in[7];
  const float* dw1   = (const float*)d_in[8];
  const float* db1   = (const float*)d_in[9];
  const float* dw2   = (const float*)d_in[10];
  const float* db2   = (const float*)d_in[11];
  const float* dw3   = (const float*)d_in[12];
  const float* db3   = (const float*)d_in[13];
  float* outp = (float*)d_out;
  float* ws = (float*)d_ws;

  float*  cbn    = ws + OFF_CBN;
  float*  ab1    = ws + OFF_AB1;
  float*  ab2    = ws + OFF_AB2;
  float*  cconst = ws + OFF_CCONST;
  float*  h2c    = ws + OFF_H2C;
  ushort* h2xh   = (ushort*)(ws + OFF_H2XH);
  ushort* h2xl   = (ushort*)(ws + OFF_H2XL);
  ushort* h3h    = (ushort*)(ws + OFF_H3H);
  ushort* h3l    = (ushort*)(ws + OFF_H3L);
  float*  scores = ws + OFF_SCORES;
  ushort* X1h    = (ushort*)(ws + OFF_X1H);
  ushort* X1l    = (ushort*)(ws + OFF_X1L);
  ushort* dw1t   = (ushort*)(ws + OFF_DW1T);
  ushort* Xh     = (ushort*)(ws + OFF_XH);
  ushort* Xl     = (ushort*)(ws + OFF_XL);
  int*    codes  = (int*)(ws + OFF_CODES);
  ushort* qbf    = (ushort*)(ws + OFF_QBF);
  float*  a1raw  = ws + OFF_A1RAW;
  float*  a2act  = ws + OFF_A2ACT;

  k_cbn<<<3584, 256, 0, stream>>>(cb, cbn);
  k_prep_ab2<<<C1, 256, 0, stream>>>(db1, dw2, db2, ab1, ab2);
  k_prep_c<<<1, 256, 0, stream>>>(dw3, db3, ab2, cconst);
  k_enc1<<<NN, 256, 0, stream>>>(audio, ew1, eb1, X1h, X1l);
  gemm_enc2<<<dim3(16, 4), 256, 0, stream>>>(ew2, X1h, X1l, eb2, h2c);
  k_h2x<<<384, 256, 0, stream>>>(h2c, h2xh, h2xl);
  gemm_h3<<<dim3(112, 4), 256, 0, stream>>>(ew3, h2xh, h2xl, eb3, h3h, h3l);
  // gemm_scores writes over X1h/X1l (dead after gemm_enc2) — stream-ordered
  gemm_scores<<<dim3(16, 4, 14), 256, 0, stream>>>(cb, h3h, h3l, cbn, scores);
  k_argmin<<<NCBK * NN, 64, 0, stream>>>(scores, codes);
  // dw1t overlaps h3h/h3l/scores memory: must launch AFTER k_argmin (stream-ordered)
  k_dw1t<<<dim3(112, 40), 256, 0, stream>>>(dw1, dw1t);
  k_gather_qbf<<<3584, 256, 0, stream>>>(cb, codes, qbf);
  gemm_a1_mfma<<<dim3(40, 4), 1024, 0, stream>>>(dw1t, qbf, a1raw);
  // Xh/Xl overlap dw1t memory: must launch AFTER gemm_a1_mfma (stream-ordered)
  k_x2<<<4096, 256, 0, stream>>>(a1raw, ab1, db1, Xh, Xl);
  gemm_dec2<<<dim3(4, 36), 256, 0, stream>>>(dw2, Xh, Xl, db2, a2act);
  k_fill<<<256, 256, 0, stream>>>(outp, cconst);
  k_dec3<<<NN, 256, 0, stream>>>(a2act, ab2, dw3, db3, outp);
}

// Round 5
// 410.331 us; speedup vs baseline: 1.3492x; 1.0768x over previous
//
#include <hip/hip_runtime.h>
#include <hip/hip_bf16.h>
#include <math.h>

#define T_IN 98304
#define SS 128
#define NBATCH 2
#define NN 256          // NBATCH*SS
#define C1 256
#define C2 512
#define C3 7168
#define NCBK 14
#define DIMV 512
#define VOC 1024
#define TOUT 97537
#define HOP 768

// ws layout (float offsets)
#define OFF_CBN    0L          // 14336
#define OFF_AB1    14336L      // 512
#define OFF_AB2    14848L      // 256
#define OFF_CCONST 15104L      // 16
#define OFF_H2C    15120L      // 131072   (n*512+ic), n=b*128+s
#define OFF_H2XH   146192L     // 196608 fl (ushort [256][1536] bf16-hi)
#define OFF_H2XL   342800L     // 196608 fl (bf16-lo)
#define OFF_H3H    539408L     // 917504 fl (ushort [256][7168] bf16-hi)
#define OFF_H3L    1456912L    // 917504 fl
#define OFF_SCORES 2374416L    // 3670016  ((k*256+n)*1024 + v)
// X1h/X1l (bf16 [256][1280] = 163840 fl each) OVERLAP scores region: X1 is dead
// before gemm_scores writes scores (same stream serializes).
#define OFF_X1H    2374416L    // ends 2538256
#define OFF_X1L    2538256L    // ends 2702096
// dw1p (bf16 fragment-packed [160 mt][224 kt][512] = 9175040 fl) OVERLAPS
// h3h/h3l/scores: all dead before k_dw1t runs (launched after k_argmin).
#define OFF_DW1T   539408L     // ends 9714448
// Xh/Xl (bf16 [2304][2560] each = 2949120 fl each) OVERLAP dw1p: dw1p is dead
// after gemm_a1_mfma; k_x2 launches after it (same stream serializes).
#define OFF_XH     539408L     // ends 3488528
#define OFF_XL     3488528L    // ends 6437648
#define OFF_CODES  9714448L    // 3584 ints
#define OFF_QBF    9718032L    // 917504 fl (bf16 fragment-packed [16 nt][224 kt][512])
#define OFF_A1RAW  10635536L   // 655360   ((n*5+j)*512 + c)  pre-bias/relu
#define OFF_A2ACT  11290896L   // 589824   ((n*9+u)*256 + o)  post-relu
// total 11880720 floats = 47.5 MB

typedef __attribute__((ext_vector_type(8))) short short8;
typedef __attribute__((ext_vector_type(4))) float f32x4;

static __device__ inline ushort f2bf(float x) {
  __hip_bfloat16 h = __float2bfloat16(x);
  return *reinterpret_cast<ushort*>(&h);
}

// exact 2-term split: x = hi + lo + O(2^-16 |x|); truncation split, residual exact
static __device__ inline void split8(const float4 x0, const float4 x1,
                                     short8& h, short8& l) {
  float xs[8] = {x0.x, x0.y, x0.z, x0.w, x1.x, x1.y, x1.z, x1.w};
  #pragma unroll
  for (int e = 0; e < 8; ++e) {
    uint b = __float_as_uint(xs[e]);
    h[e] = (short)(b >> 16);
    float r = xs[e] - __uint_as_float(b & 0xffff0000u);
    l[e] = (short)(__float_as_uint(r) >> 16);
  }
}

// ---------------- prep: codebook norms ----------------
__global__ void k_cbn(const float* __restrict__ cb, float* __restrict__ cbn) {
  int row = blockIdx.x * 4 + (threadIdx.x >> 6);
  int lane = threadIdx.x & 63;
  const float* p = cb + (long)row * DIMV;
  float s = 0.f;
  for (int d = lane; d < DIMV; d += 64) { float x = p[d]; s += x * x; }
  for (int off = 32; off; off >>= 1) s += __shfl_down(s, off);
  if (lane == 0) cbn[row] = s;
}

// ---------------- prep A: ab1 = relu(db1); ab2[o] = relu(db2[o]+sum_c W(o,c)*ab1[c])
__global__ __launch_bounds__(256) void k_prep_ab2(const float* __restrict__ db1,
    const float* __restrict__ dw2, const float* __restrict__ db2,
    float* __restrict__ ab1, float* __restrict__ ab2) {
  __shared__ float red[256];
  int o = blockIdx.x, t = threadIdx.x;
  if (o == 0) { ab1[t] = fmaxf(db1[t], 0.f); ab1[t + 256] = fmaxf(db1[t + 256], 0.f); }
  const float* wp = dw2 + (long)o * C2 * 5;
  float acc = 0.f;
  #pragma unroll
  for (int h = 0; h < 2; ++h) {
    int c = t + h * 256;
    const float* p = wp + c * 5;
    float wsum = p[0] + p[1] + p[2] + p[3] + p[4];
    acc = fmaf(wsum, fmaxf(db1[c], 0.f), acc);
  }
  red[t] = acc;
  __syncthreads();
  for (int off = 128; off; off >>= 1) {
    if (t < off) red[t] += red[t + off];
    __syncthreads();
  }
  if (t == 0) ab2[o] = fmaxf(red[0] + db2[o], 0.f);
}

// ---------------- prep B: cconst = tanh(db3 + sum_o (sum_j dw3[o][j]) * ab2[o]) ----
__global__ __launch_bounds__(256) void k_prep_c(const float* __restrict__ dw3,
    const float* __restrict__ db3, const float* __restrict__ ab2,
    float* __restrict__ cconst) {
  __shared__ float red[256];
  int t = threadIdx.x;
  float wsum3 = 0.f;
  #pragma unroll
  for (int j = 0; j < 7; ++j) wsum3 += dw3[t*7+j];
  red[t] = wsum3 * ab2[t];
  __syncthreads();
  for (int off = 128; off; off >>= 1) {
    if (t < off) red[t] += red[t + off];
    __syncthreads();
  }
  if (t == 0) cconst[0] = tanhf(red[0] + db3[0]);
}

// ---------------- encoder conv1 (k7,p3) at the 5 cols conv2 needs, as im2col ------
// X1[n][ic*5+jj] = h1[b][ic][768s+jj-2]  (0 if tcol<0: conv2 zero pad)
__global__ __launch_bounds__(256) void k_enc1(const float* __restrict__ audio,
    const float* __restrict__ ew1, const float* __restrict__ eb1,
    ushort* __restrict__ X1h, ushort* __restrict__ X1l) {
  int n = blockIdx.x, ic = threadIdx.x;
  int b = n >> 7, s = n & 127;
  const float* ap = audio + (long)b * T_IN;
  int base = HOP * s - 5;           // audio idx for window pos 0
  float a[11];
  #pragma unroll
  for (int w = 0; w < 11; ++w) {
    int ai = base + w;
    a[w] = (ai >= 0 && ai < T_IN) ? ap[ai] : 0.f;
  }
  float w1[7];
  #pragma unroll
  for (int j = 0; j < 7; ++j) w1[j] = ew1[ic*7+j];
  float b1 = eb1[ic];
  long off = (long)n * 1280 + ic * 5;
  #pragma unroll
  for (int jj = 0; jj < 5; ++jj) {
    int tcol = HOP * s + jj - 2;
    float v = 0.f;
    if (tcol >= 0) {
      float acc = b1;
      #pragma unroll
      for (int j = 0; j < 7; ++j) acc = fmaf(w1[j], a[jj + j], acc);
      v = fmaxf(acc, 0.f);
    }
    uint bi = __float_as_uint(v);
    X1h[off + jj] = (ushort)(bi >> 16);
    float r = v - __uint_as_float(bi & 0xffff0000u);
    X1l[off + jj] = (ushort)(__float_as_uint(r) >> 16);
  }
}

// ---------------- encoder conv2 as GEMM: h2c[n][oc] = relu(eb2 + ew2 . X1^T) ------
// 4-wave blocks, disjoint K-quarter (320) per wave, barrier-free K-loop,
// LDS reduce epilogue (wave w reduces chunks 2w, 2w+1).
__global__ __launch_bounds__(256) void gemm_enc2(const float* __restrict__ ew2,
    const ushort* __restrict__ X1h, const ushort* __restrict__ X1l,
    const float* __restrict__ eb2, float* __restrict__ h2c) {
  __shared__ __align__(16) float red[4 * 2048];   // 32 KB: [wave][chunk 0..7][lane][4]
  const int tid = threadIdx.x;
  const int w = tid >> 6, lane = tid & 63;
  const int l15 = lane & 15, quad = lane >> 4;
  const int m0 = blockIdx.x * 32, n0 = blockIdx.y * 64;
  const int kbase = w * 320;                  // disjoint K-quarter per wave
  f32x4 acc[2][4] = {};
  const float*  aB = ew2 + (long)(m0 + l15) * 1280 + kbase + quad * 8;
  const ushort* bhB = X1h + (long)(n0 + l15) * 1280 + kbase + quad * 8;
  const ushort* blB = X1l + (long)(n0 + l15) * 1280 + kbase + quad * 8;
  for (int k0 = 0; k0 < 320; k0 += 32) {
    short8 ah[2], al[2], bh[4], bl[4];
    #pragma unroll
    for (int f = 0; f < 2; ++f) {
      const float* ap = aB + (long)f * 16 * 1280 + k0;
      float4 x0 = *(const float4*)ap;
      float4 x1 = *(const float4*)(ap + 4);
      split8(x0, x1, ah[f], al[f]);
    }
    #pragma unroll
    for (int f = 0; f < 4; ++f) {
      bh[f] = *(const short8*)(bhB + (long)f * 16 * 1280 + k0);
      bl[f] = *(const short8*)(blB + (long)f * 16 * 1280 + k0);
    }
    #pragma unroll
    for (int i = 0; i < 2; ++i)
      #pragma unroll
      for (int j = 0; j < 4; ++j) {
        acc[i][j] = __builtin_amdgcn_mfma_f32_16x16x32_bf16(ah[i], bh[j], acc[i][j], 0, 0, 0);
        acc[i][j] = __builtin_amdgcn_mfma_f32_16x16x32_bf16(ah[i], bl[j], acc[i][j], 0, 0, 0);
        acc[i][j] = __builtin_amdgcn_mfma_f32_16x16x32_bf16(al[i], bh[j], acc[i][j], 0, 0, 0);
      }
  }
  #pragma unroll
  for (int i = 0; i < 2; ++i)
    #pragma unroll
    for (int j = 0; j < 4; ++j)
      *(float4*)&red[w * 2048 + (i * 4 + j) * 256 + lane * 4] = *(float4*)&acc[i][j];
  __syncthreads();
  #pragma unroll
  for (int q = 0; q < 2; ++q) {
    const int c = 2 * w + q;
    const int i = c >> 2, j = c & 3;
    float4 s = make_float4(0.f, 0.f, 0.f, 0.f);
    #pragma unroll
    for (int g = 0; g < 4; ++g) {
      float4 t4 = *(const float4*)&red[g * 2048 + c * 256 + lane * 4];
      s.x += t4.x; s.y += t4.y; s.z += t4.z; s.w += t4.w;
    }
    const int obase = m0 + i * 16 + quad * 4;
    float4 bias = *(const float4*)(eb2 + obase);
    const int n = n0 + j * 16 + l15;
    float4 out;
    out.x = fmaxf(s.x + bias.x, 0.f);
    out.y = fmaxf(s.y + bias.y, 0.f);
    out.z = fmaxf(s.z + bias.z, 0.f);
    out.w = fmaxf(s.w + bias.w, 0.f);
    *(float4*)(h2c + (long)n * C2 + obase) = out;
  }
}

// ---------------- im2col for conv3 (k3,p1), written as bf16 hi/lo split ----------
__global__ void k_h2x(const float* __restrict__ h2c, ushort* __restrict__ h2xh,
                      ushort* __restrict__ h2xl) {
  int idx = blockIdx.x * 256 + threadIdx.x;
  const int total = NN * 1536;
  for (; idx < total; idx += gridDim.x * 256) {
    int n = idx / 1536, r = idx - n * 1536;
    int ic = r / 3, j = r - ic * 3;
    int s2 = (n & 127) + j - 1;
    int b = n >> 7;
    float v = (s2 >= 0 && s2 < SS) ? h2c[(long)(b*SS + s2)*C2 + ic] : 0.f;
    uint bi = __float_as_uint(v);
    h2xh[idx] = (ushort)(bi >> 16);
    float rr = v - __uint_as_float(bi & 0xffff0000u);
    h2xl[idx] = (ushort)(__float_as_uint(rr) >> 16);
  }
}

// ---------------- S1: h3 = ew3 . h2x^T + eb3 ----------------
// 4-wave blocks, disjoint K-quarter (384) per wave, barrier-free K-loop,
// LDS reduce epilogue.
__global__ __launch_bounds__(256) void gemm_h3(const float* __restrict__ A,
    const ushort* __restrict__ Bh, const ushort* __restrict__ Bl,
    const float* __restrict__ eb3, ushort* __restrict__ h3h, ushort* __restrict__ h3l) {
  __shared__ __align__(16) float red[4 * 4096];   // 64 KB
  const int tid = threadIdx.x;
  const int w = tid >> 6, lane = tid & 63;
  const int l15 = lane & 15, quad = lane >> 4;
  const int m0 = blockIdx.x * 64, n0 = blockIdx.y * 64;
  const int kbase = w * 384;                  // disjoint K-quarter per wave
  f32x4 acc[4][4] = {};
  const float*  aB = A  + (long)(m0 + l15) * 1536 + kbase + quad * 8;
  const ushort* bhB = Bh + (long)(n0 + l15) * 1536 + kbase + quad * 8;
  const ushort* blB = Bl + (long)(n0 + l15) * 1536 + kbase + quad * 8;
  for (int k0 = 0; k0 < 384; k0 += 32) {
    short8 ah[4], al[4], bh[4], bl[4];
    #pragma unroll
    for (int f = 0; f < 4; ++f) {
      const float* ap = aB + (long)f * 16 * 1536 + k0;
      float4 x0 = *(const float4*)ap;
      float4 x1 = *(const float4*)(ap + 4);
      split8(x0, x1, ah[f], al[f]);
      bh[f] = *(const short8*)(bhB + (long)f * 16 * 1536 + k0);
      bl[f] = *(const short8*)(blB + (long)f * 16 * 1536 + k0);
    }
    #pragma unroll
    for (int i = 0; i < 4; ++i)
      #pragma unroll
      for (int j = 0; j < 4; ++j) {
        acc[i][j] = __builtin_amdgcn_mfma_f32_16x16x32_bf16(ah[i], bh[j], acc[i][j], 0, 0, 0);
        acc[i][j] = __builtin_amdgcn_mfma_f32_16x16x32_bf16(ah[i], bl[j], acc[i][j], 0, 0, 0);
        acc[i][j] = __builtin_amdgcn_mfma_f32_16x16x32_bf16(al[i], bh[j], acc[i][j], 0, 0, 0);
      }
  }
  // stash partials: region w, chunk (i*4+j), lane-contiguous float4 (2-way = free)
  #pragma unroll
  for (int i = 0; i < 4; ++i)
    #pragma unroll
    for (int j = 0; j < 4; ++j)
      *(float4*)&red[w * 4096 + (i * 4 + j) * 256 + lane * 4] = *(float4*)&acc[i][j];
  __syncthreads();
  // wave w reduces the 4 K-partials for row-block i=w, adds bias, packs hi/lo
  const int mbase = m0 + w * 16 + quad * 4;
  float4 bias = *(const float4*)(eb3 + mbase);
  #pragma unroll
  for (int j = 0; j < 4; ++j) {
    float4 s = *(const float4*)&red[(w * 4 + j) * 256 + lane * 4];
    #pragma unroll
    for (int r = 1; r < 4; ++r) {
      float4 tt = *(const float4*)&red[r * 4096 + (w * 4 + j) * 256 + lane * 4];
      s.x += tt.x; s.y += tt.y; s.z += tt.z; s.w += tt.w;
    }
    const int n = n0 + j * 16 + l15;
    float v0 = s.x + bias.x;
    float v1 = s.y + bias.y;
    float v2 = s.z + bias.z;
    float v3 = s.w + bias.w;
    uint b0 = __float_as_uint(v0), b1 = __float_as_uint(v1);
    uint b2 = __float_as_uint(v2), b3 = __float_as_uint(v3);
    uint2 hp;
    hp.x = (b0 >> 16) | (b1 & 0xffff0000u);
    hp.y = (b2 >> 16) | (b3 & 0xffff0000u);
    float r0 = v0 - __uint_as_float(b0 & 0xffff0000u);
    float r1 = v1 - __uint_as_float(b1 & 0xffff0000u);
    float r2 = v2 - __uint_as_float(b2 & 0xffff0000u);
    float r3 = v3 - __uint_as_float(b3 & 0xffff0000u);
    uint2 lp;
    lp.x = (__float_as_uint(r0) >> 16) | (__float_as_uint(r1) & 0xffff0000u);
    lp.y = (__float_as_uint(r2) >> 16) | (__float_as_uint(r3) & 0xffff0000u);
    long off = (long)n * C3 + mbase;
    *(uint2*)(h3h + off) = hp;
    *(uint2*)(h3l + off) = lp;
  }
}

// ---------------- S2: scores = cbn - 2*cb.h3^T ----------------
// 4-wave blocks, disjoint K-quarter (128) per wave, barrier-free K-loop,
// LDS reduce epilogue.
__global__ __launch_bounds__(256) void gemm_scores(const float* __restrict__ cb,
    const ushort* __restrict__ h3h, const ushort* __restrict__ h3l,
    const float* __restrict__ cbn, float* __restrict__ scores) {
  __shared__ __align__(16) float red[4 * 4096];   // 64 KB
  const int tid = threadIdx.x;
  const int w = tid >> 6, lane = tid & 63;
  const int l15 = lane & 15, quad = lane >> 4;
  const int m0 = blockIdx.x * 64, n0 = blockIdx.y * 64, z = blockIdx.z;
  const int kbase = w * 128;                  // disjoint K-quarter per wave
  f32x4 acc[4][4] = {};
  const float*  aB = cb + (long)z * VOC * DIMV + (long)(m0 + l15) * 512 + kbase + quad * 8;
  const ushort* bhB = h3h + (long)(n0 + l15) * C3 + z * 512 + kbase + quad * 8;
  const ushort* blB = h3l + (long)(n0 + l15) * C3 + z * 512 + kbase + quad * 8;
  for (int k0 = 0; k0 < 128; k0 += 32) {
    short8 ah[4], al[4], bh[4], bl[4];
    #pragma unroll
    for (int f = 0; f < 4; ++f) {
      const float* ap = aB + (long)f * 16 * 512 + k0;
      float4 x0 = *(const float4*)ap;
      float4 x1 = *(const float4*)(ap + 4);
      split8(x0, x1, ah[f], al[f]);
      bh[f] = *(const short8*)(bhB + (long)f * 16 * C3 + k0);
      bl[f] = *(const short8*)(blB + (long)f * 16 * C3 + k0);
    }
    #pragma unroll
    for (int i = 0; i < 4; ++i)
      #pragma unroll
      for (int j = 0; j < 4; ++j) {
        acc[i][j] = __builtin_amdgcn_mfma_f32_16x16x32_bf16(ah[i], bh[j], acc[i][j], 0, 0, 0);
        acc[i][j] = __builtin_amdgcn_mfma_f32_16x16x32_bf16(ah[i], bl[j], acc[i][j], 0, 0, 0);
        acc[i][j] = __builtin_amdgcn_mfma_f32_16x16x32_bf16(al[i], bh[j], acc[i][j], 0, 0, 0);
      }
  }
  // stash partials
  #pragma unroll
  for (int i = 0; i < 4; ++i)
    #pragma unroll
    for (int j = 0; j < 4; ++j)
      *(float4*)&red[w * 4096 + (i * 4 + j) * 256 + lane * 4] = *(float4*)&acc[i][j];
  __syncthreads();
  // wave w reduces the 4 K-partials for row-block i=w, applies cbn - 2*acc
  const int vbase = m0 + w * 16 + quad * 4;
  float4 cn = *(const float4*)(cbn + z * VOC + vbase);
  #pragma unroll
  for (int j = 0; j < 4; ++j) {
    float4 s = *(const float4*)&red[(w * 4 + j) * 256 + lane * 4];
    #pragma unroll
    for (int r = 1; r < 4; ++r) {
      float4 tt = *(const float4*)&red[r * 4096 + (w * 4 + j) * 256 + lane * 4];
      s.x += tt.x; s.y += tt.y; s.z += tt.z; s.w += tt.w;
    }
    const int n = n0 + j * 16 + l15;
    float4 out;
    out.x = cn.x - 2.f * s.x;
    out.y = cn.y - 2.f * s.y;
    out.z = cn.z - 2.f * s.z;
    out.w = cn.w - 2.f * s.w;
    *(float4*)(scores + ((long)z * NN + n) * VOC + vbase) = out;
  }
}

// ---------------- argmin over 1024 codes, numpy tie-break (lowest v) ----------------
__global__ void k_argmin(const float* __restrict__ scores, int* __restrict__ codes) {
  int row = blockIdx.x;          // k*256+n
  int lane = threadIdx.x;        // 64
  const float* p = scores + (long)row * VOC;
  float best = 3.4e38f; int bi = 0;
  for (int i = 0; i < 16; ++i) {
    int v = i * 64 + lane;
    float x = p[v];
    if (x < best) { best = x; bi = v; }
  }
  for (int off = 32; off; off >>= 1) {
    float ob = __shfl_down(best, off);
    int oi = __shfl_down(bi, off);
    if (ob < best || (ob == best && oi < bi)) { best = ob; bi = oi; }
  }
  if (lane == 0) codes[row] = bi;
}

// ---------------- transpose+convert dw1 [7168][2560] fp32 -> fragment-packed bf16 ----
// dw1p[(mt*224 + kt)*512 + (quad*16 + l15)*8 + e] = bf16(dw1[kt*32+quad*8+e][mt*16+l15])
// so a wave's MFMA A-fragment load (lane = quad*16+l15 reads 8 elems) is one
// contiguous 1 KB block: lane i at base + 16*i. (Coalescing fix for gemm_a1.)
__global__ __launch_bounds__(256) void k_dw1t(const float* __restrict__ dw1,
                                              ushort* __restrict__ dw1p) {
  __shared__ __align__(16) ushort T[64 * 72];   // [m][k] tile, pitch 72
  int t = threadIdx.x;
  int k0 = blockIdx.x * 64, m0 = blockIdx.y * 64;
  int kk = t >> 2, mj = (t & 3) * 16;
  const float* src = dw1 + (long)(k0 + kk) * 2560 + m0 + mj;
  float x[16];
  *(float4*)&x[0]  = *(const float4*)(src);
  *(float4*)&x[4]  = *(const float4*)(src + 4);
  *(float4*)&x[8]  = *(const float4*)(src + 8);
  *(float4*)&x[12] = *(const float4*)(src + 12);
  #pragma unroll
  for (int l = 0; l < 16; ++l)
    T[(mj + l) * 72 + kk] = f2bf(x[l]);
  __syncthreads();
  int mo = t >> 2, kc = (t & 3) * 16;
  const int m = m0 + mo;
  const int mt = m >> 4, l15 = m & 15;
  #pragma unroll
  for (int h = 0; h < 2; ++h) {
    const int kk0 = kc + h * 8;              // k within 64-tile, 8-aligned
    const int kglob = k0 + kk0;
    const int kt = kglob >> 5;
    const int quad = (kglob >> 3) & 3;
    uint4 u = *(const uint4*)&T[mo * 72 + kk0];
    *(uint4*)(dw1p + ((long)(mt * 224 + kt)) * 512 + (quad * 16 + l15) * 8) = u;
  }
}

// ---------------- gather q as bf16 fragments ----------------
// qp[(nt*224 + kt)*512 + (quad*16+l15)*8 + e] = bf16(cb[kcb, code(kcb,n), d])
// where n = nt*16+l15, kglob = kt*32+quad*8+e, kcb = kglob/512, d = kglob%512.
__global__ void k_gather_qbf(const float* __restrict__ cb, const int* __restrict__ codes,
                             ushort* __restrict__ qp) {
  int o = blockIdx.x * 256 + threadIdx.x;        // uint4 index
  const int total = NN * C3 / 8;                 // 229376
  if (o >= total) return;
  int frag = o >> 6, r = o & 63;
  int quad = r >> 4, l15 = r & 15;
  int nt = frag / 224, kt = frag - nt * 224;
  int n = nt * 16 + l15;
  int kglob = kt * 32 + quad * 8;
  int kcb = kglob >> 9, d0 = kglob & 511;
  int code = codes[kcb * NN + n];
  const float* s = cb + ((long)(kcb * VOC + code)) * DIMV + d0;
  float4 x0 = *(const float4*)s;
  float4 x1 = *(const float4*)(s + 4);
  uint4 u;
  u.x = (uint)f2bf(x0.x) | ((uint)f2bf(x0.y) << 16);
  u.y = (uint)f2bf(x0.z) | ((uint)f2bf(x0.w) << 16);
  u.z = (uint)f2bf(x1.x) | ((uint)f2bf(x1.y) << 16);
  u.w = (uint)f2bf(x1.z) | ((uint)f2bf(x1.w) << 16);
  ((uint4*)qp)[o] = u;
}

// ---------------- decoder convT GEMM via MFMA bf16 ----------------
// Fragment-packed operands: every K-loop load is a contiguous 1 KB wave load
// (lane i at base+16i) — coalescing fix. Old row-strided gathers (16 scattered
// 64B segments per load) were transaction-bound at 63 us regardless of
// occupancy (round-3 A/B: 4-wave and 16-wave both 63 us, MfmaUtil 5.4%).
// 16-wave blocks, disjoint K-1/16 per wave (14 kt), staged 4-round LDS reduce.
__global__ __launch_bounds__(1024) void gemm_a1_mfma(const ushort* __restrict__ dw1p,
    const ushort* __restrict__ qp, float* __restrict__ a1raw) {
  // red[region 0..3][chunk 0..15][lane][4] = 64 KB
  __shared__ __align__(16) float red[4 * 4096];
  const int tid = threadIdx.x;
  const int w = tid >> 6, lane = tid & 63;     // w in 0..15
  const int l15 = lane & 15, quad = lane >> 4;
  const int mt0 = blockIdx.x * 4, nt0 = blockIdx.y * 4;
  const int kt0 = w * 14;                      // disjoint 14 k-tiles per wave
  f32x4 acc[4][4] = {};
  const ushort* aB = dw1p + ((long)(mt0 * 224 + kt0)) * 512 + lane * 8;
  const ushort* bB = qp   + ((long)(nt0 * 224 + kt0)) * 512 + lane * 8;
  #pragma unroll 2
  for (int kt = 0; kt < 14; ++kt) {
    short8 ah[4], bh[4];
    #pragma unroll
    for (int f = 0; f < 4; ++f) {
      ah[f] = *(const short8*)(aB + ((long)(f * 224 + kt)) * 512);
      bh[f] = *(const short8*)(bB + ((long)(f * 224 + kt)) * 512);
    }
    #pragma unroll
    for (int i = 0; i < 4; ++i)
      #pragma unroll
      for (int j = 0; j < 4; ++j)
        acc[i][j] = __builtin_amdgcn_mfma_f32_16x16x32_bf16(ah[i], bh[j], acc[i][j], 0, 0, 0);
  }
  // staged 4-round cross-wave reduce: round r, waves 4r..4r+3 stash all 16
  // chunks; every wave accumulates its owned chunk (c = w) in registers.
  float4 rsum = make_float4(0.f, 0.f, 0.f, 0.f);
  #pragma unroll
  for (int r = 0; r < 4; ++r) {
    if ((w >> 2) == r) {
      #pragma unroll
      for (int i = 0; i < 4; ++i)
        #pragma unroll
        for (int j = 0; j < 4; ++j)
          *(float4*)&red[(w & 3) * 4096 + (i * 4 + j) * 256 + lane * 4] = *(float4*)&acc[i][j];
    }
    __syncthreads();
    #pragma unroll
    for (int g = 0; g < 4; ++g) {
      float4 t4 = *(const float4*)&red[g * 4096 + w * 256 + lane * 4];
      rsum.x += t4.x; rsum.y += t4.y; rsum.z += t4.z; rsum.w += t4.w;
    }
    __syncthreads();
  }
  // wave w holds the final sum for chunk (i = w>>2, j = w&3); scatter to a1raw
  const int ci = w >> 2, cj = w & 3;
  const int n = nt0 * 16 + cj * 16 + l15;
  const int mb = mt0 * 16 + ci * 16 + quad * 4;
  float v[4] = {rsum.x, rsum.y, rsum.z, rsum.w};
  #pragma unroll
  for (int reg = 0; reg < 4; ++reg) {
    int m = mb + reg;
    int c = m / 5, jj = m - c * 5;
    a1raw[((long)(n * 5 + jj)) * C2 + c] = v[reg];
  }
}

// ---------------- k_x2: build conv2 im2col X (bf16 hi/lo) from a1raw/ab1 ----------
__global__ void k_x2(const float* __restrict__ a1raw, const float* __restrict__ ab1g,
                     const float* __restrict__ db1, ushort* __restrict__ Xh,
                     ushort* __restrict__ Xl) {
  int idx = blockIdx.x * 256 + threadIdx.x;
  const int total = 2304 * 2560;
  for (; idx < total; idx += gridDim.x * 256) {
    int nu = idx / 2560, ck = idx - nu * 2560;
    int n = nu / 9, u = nu - n * 9;
    int c = ck / 5, jj = ck - c * 5;
    int w = u + jj;
    int s = n & 127;
    int tc = HOP * s - 6 + w;
    float v;
    if (tc < 0 || tc > TOUT - 1) v = 0.f;
    else if (w >= 4 && w <= 8)
      v = fmaxf(db1[c] + a1raw[((long)(n * 5 + (w - 4))) * C2 + c], 0.f);
    else v = ab1g[c];
    uint bi = __float_as_uint(v);
    Xh[idx] = (ushort)(bi >> 16);
    float rr = v - __uint_as_float(bi & 0xffff0000u);
    Xl[idx] = (ushort)(__float_as_uint(rr) >> 16);
  }
}

// ---------------- decoder conv2 as GEMM: a2act = relu(db2 + dw2 . X^T) ----------
// 4-wave blocks, disjoint K-quarter (640) per wave, barrier-free K-loop with
// direct loads (A fp32 split OTF), LDS reduce epilogue.
__global__ __launch_bounds__(256) void gemm_dec2(const float* __restrict__ dw2,
    const ushort* __restrict__ Xh, const ushort* __restrict__ Xl,
    const float* __restrict__ db2, float* __restrict__ a2act) {
  __shared__ __align__(16) float red[4 * 4096];   // 64 KB
  const int tid = threadIdx.x;
  const int w = tid >> 6, lane = tid & 63;
  const int l15 = lane & 15, quad = lane >> 4;
  const int m0 = blockIdx.x * 64, n0 = blockIdx.y * 64;
  const int kbase = w * 640;                  // disjoint K-quarter per wave
  f32x4 acc[4][4] = {};
  const float*  aB = dw2 + (long)(m0 + l15) * 2560 + kbase + quad * 8;
  const ushort* bhB = Xh + (long)(n0 + l15) * 2560 + kbase + quad * 8;
  const ushort* blB = Xl + (long)(n0 + l15) * 2560 + kbase + quad * 8;
  for (int k0 = 0; k0 < 640; k0 += 32) {
    short8 ah[4], al[4], bh[4], bl[4];
    #pragma unroll
    for (int f = 0; f < 4; ++f) {
      const float* ap = aB + (long)f * 16 * 2560 + k0;
      float4 x0 = *(const float4*)ap;
      float4 x1 = *(const float4*)(ap + 4);
      split8(x0, x1, ah[f], al[f]);
      bh[f] = *(const short8*)(bhB + (long)f * 16 * 2560 + k0);
      bl[f] = *(const short8*)(blB + (long)f * 16 * 2560 + k0);
    }
    #pragma unroll
    for (int i = 0; i < 4; ++i)
      #pragma unroll
      for (int j = 0; j < 4; ++j) {
        acc[i][j] = __builtin_amdgcn_mfma_f32_16x16x32_bf16(ah[i], bh[j], acc[i][j], 0, 0, 0);
        acc[i][j] = __builtin_amdgcn_mfma_f32_16x16x32_bf16(ah[i], bl[j], acc[i][j], 0, 0, 0);
        acc[i][j] = __builtin_amdgcn_mfma_f32_16x16x32_bf16(al[i], bh[j], acc[i][j], 0, 0, 0);
      }
  }
  // stash partials: region w, chunk (i*4+j), lane-contiguous float4 (2-way = free)
  #pragma unroll
  for (int i = 0; i < 4; ++i)
    #pragma unroll
    for (int j = 0; j < 4; ++j)
      *(float4*)&red[w * 4096 + (i * 4 + j) * 256 + lane * 4] = *(float4*)&acc[i][j];
  __syncthreads();
  // wave w reduces the 4 K-partials for row-block i=w, applies bias+relu, stores
  const int mb = m0 + w * 16 + quad * 4;
  float4 bias = *(const float4*)(db2 + mb);
  #pragma unroll
  for (int j = 0; j < 4; ++j) {
    float4 s = *(const float4*)&red[(w * 4 + j) * 256 + lane * 4];
    #pragma unroll
    for (int r = 1; r < 4; ++r) {
      float4 tt = *(const float4*)&red[r * 4096 + (w * 4 + j) * 256 + lane * 4];
      s.x += tt.x; s.y += tt.y; s.z += tt.z; s.w += tt.w;
    }
    const int nu = n0 + j * 16 + l15;
    float4 out;
    out.x = fmaxf(s.x + bias.x, 0.f);
    out.y = fmaxf(s.y + bias.y, 0.f);
    out.z = fmaxf(s.z + bias.z, 0.f);
    out.w = fmaxf(s.w + bias.w, 0.f);
    *(float4*)(a2act + (long)nu * C1 + mb) = out;
  }
}

// ---------------- fill output with the constant tanh value ----------------
__global__ void k_fill(float* __restrict__ outp, const float* __restrict__ cconst) {
  float v = cconst[0];
  int idx = blockIdx.x * 256 + threadIdx.x;
  const int total = NBATCH * TOUT;
  for (; idx < total; idx += gridDim.x * 256) outp[idx] = v;
}

// ---------------- decoder conv3+tanh on 15 active cols per (b,s) ----------------
__global__ __launch_bounds__(256) void k_dec3(const float* __restrict__ a2act,
    const float* __restrict__ ab2g, const float* __restrict__ dw3,
    const float* __restrict__ db3, float* __restrict__ outp) {
  __shared__ float sa2[9 * C1];
  __shared__ float sb[C1];
  int n = blockIdx.x;
  int s = n & 127, b = n >> 7;
  int t = threadIdx.x;
  for (int i = t; i < 9 * C1; i += 256) sa2[i] = a2act[(long)n * 9 * C1 + i];
  sb[t] = ab2g[t];
  __syncthreads();
  int wv = t >> 6, lane = t & 63;
  float b3 = db3[0];
  for (int w15 = wv; w15 < 15; w15 += 4) {
    int tc = HOP * s - 7 + w15;
    if (tc < 0 || tc > TOUT - 1) continue;
    float part = 0.f;
    for (int cc = lane; cc < C1; cc += 64) {
      #pragma unroll
      for (int j = 0; j < 7; ++j) {
        int wcol = tc + j - 3;
        float x;
        if (wcol < 0 || wcol > TOUT - 1) x = 0.f;
        else {
          int du = wcol - (HOP * s - 4);
          x = (du >= 0 && du <= 8) ? sa2[du * C1 + cc] : sb[cc];
        }
        part = fmaf(dw3[cc*7+j], x, part);
      }
    }
    for (int off = 32; off; off >>= 1) part += __shfl_down(part, off);
    if (lane == 0) outp[(long)b * TOUT + tc] = tanhf(part + b3);
  }
}

extern "C" void kernel_launch(void* const* d_in, const int* in_sizes, int n_in,
                              void* d_out, int out_size, void* d_ws, size_t ws_size,
                              hipStream_t stream) {
  const float* audio = (const float*)d_in[0];
  const float* cb    = (const float*)d_in[1];
  const float* ew1   = (const float*)d_in[2];
  const float* eb1   = (const float*)d_in[3];
  const float* ew2   = (const float*)d_in[4];
  const float* eb2   = (const float*)d_in[5];
  const float* ew3   = (const float*)d_in[6];
  const float* eb3   = (const float*)d_in[7];
  const float* dw1   = (const float*)d_in[8];
  const float* db1   = (const float*)d_in[9];
  const float* dw2   = (const float*)d_in[10];
  const float* db2   = (const float*)d_in[11];
  const float* dw3   = (const float*)d_in[12];
  const float* db3   = (const float*)d_in[13];
  float* outp = (float*)d_out;
  float* ws = (float*)d_ws;

  float*  cbn    = ws + OFF_CBN;
  float*  ab1    = ws + OFF_AB1;
  float*  ab2    = ws + OFF_AB2;
  float*  cconst = ws + OFF_CCONST;
  float*  h2c    = ws + OFF_H2C;
  ushort* h2xh   = (ushort*)(ws + OFF_H2XH);
  ushort* h2xl   = (ushort*)(ws + OFF_H2XL);
  ushort* h3h    = (ushort*)(ws + OFF_H3H);
  ushort* h3l    = (ushort*)(ws + OFF_H3L);
  float*  scores = ws + OFF_SCORES;
  ushort* X1h    = (ushort*)(ws + OFF_X1H);
  ushort* X1l    = (ushort*)(ws + OFF_X1L);
  ushort* dw1p   = (ushort*)(ws + OFF_DW1T);
  ushort* Xh     = (ushort*)(ws + OFF_XH);
  ushort* Xl     = (ushort*)(ws + OFF_XL);
  int*    codes  = (int*)(ws + OFF_CODES);
  ushort* qp     = (ushort*)(ws + OFF_QBF);
  float*  a1raw  = ws + OFF_A1RAW;
  float*  a2act  = ws + OFF_A2ACT;

  k_cbn<<<3584, 256, 0, stream>>>(cb, cbn);
  k_prep_ab2<<<C1, 256, 0, stream>>>(db1, dw2, db2, ab1, ab2);
  k_prep_c<<<1, 256, 0, stream>>>(dw3, db3, ab2, cconst);
  k_enc1<<<NN, 256, 0, stream>>>(audio, ew1, eb1, X1h, X1l);
  gemm_enc2<<<dim3(16, 4), 256, 0, stream>>>(ew2, X1h, X1l, eb2, h2c);
  k_h2x<<<384, 256, 0, stream>>>(h2c, h2xh, h2xl);
  gemm_h3<<<dim3(112, 4), 256, 0, stream>>>(ew3, h2xh, h2xl, eb3, h3h, h3l);
  // gemm_scores writes over X1h/X1l (dead after gemm_enc2) — stream-ordered
  gemm_scores<<<dim3(16, 4, 14), 256, 0, stream>>>(cb, h3h, h3l, cbn, scores);
  k_argmin<<<NCBK * NN, 64, 0, stream>>>(scores, codes);
  // dw1p overlaps h3h/h3l/scores memory: must launch AFTER k_argmin (stream-ordered)
  k_dw1t<<<dim3(112, 40), 256, 0, stream>>>(dw1, dw1p);
  k_gather_qbf<<<896, 256, 0, stream>>>(cb, codes, qp);
  gemm_a1_mfma<<<dim3(40, 4), 1024, 0, stream>>>(dw1p, qp, a1raw);
  // Xh/Xl overlap dw1p memory: must launch AFTER gemm_a1_mfma (stream-ordered)
  k_x2<<<4096, 256, 0, stream>>>(a1raw, ab1, db1, Xh, Xl);
  gemm_dec2<<<dim3(4, 36), 256, 0, stream>>>(dw2, Xh, Xl, db2, a2act);
  k_fill<<<256, 256, 0, stream>>>(outp, cconst);
  k_dec3<<<NN, 256, 0, stream>>>(a2act, ab2, dw3, db3, outp);
}